// Round 3
// baseline (1095.333 us; speedup 1.0000x reference)
//
#include <hip/hip_runtime.h>
#include <cstdint>
#include <cstddef>

// ---------------------------------------------------------------------------
// VQ-VAE forward. B=16384 F=4096 H=512 D=64 M=8 K=512
// Out (floats): [idx 131072][z_e 8388608][z_q 8388608][emb 8388608][X 67108864]
// enc1 in fp16x2-split MFMA (Dekker split: fp32-accurate, argmin-safe).
//   BM=64 BN=256 BK=32, 4 waves, 80 KB LDS -> 2 blocks/CU (cross-block overlap)
// enc2/enc3/dec1/dec2 fp32 (small). dec3 in bf16 MFMA (sigmoid tail).
// Split-K partials staged in o_X (written last by dec3).
// ws (25.2 MB): h1 | h2 ; decoder phase reuses: g1 | g2b(bf16) | WT(bf16)
// We1^T fp16 hi/lo lives in the high region of o_X (dead until dec3).
// ---------------------------------------------------------------------------

static constexpr int BB = 16384;
static constexpr int TM = 128, TN = 128, TK = 16;

typedef __attribute__((ext_vector_type(8))) short short8;
typedef __attribute__((ext_vector_type(8))) _Float16 half8;
typedef __attribute__((ext_vector_type(4))) float f32x4;

__device__ __forceinline__ unsigned short f2bf(float f) {
    union { float f; uint32_t u; } v; v.f = f;
    uint32_t r = (v.u + 0x7FFFu + ((v.u >> 16) & 1u)) >> 16;
    return (unsigned short)r;
}

// staggered Bs column mapping: breaks the tx*8 4-way bank conflict
__device__ __forceinline__ int bsw(int c) { return c + ((c >> 5) << 2); }

#define GLL16(gp, lp) \
    __builtin_amdgcn_global_load_lds( \
        (const __attribute__((address_space(1))) uint32_t*)(gp), \
        (__attribute__((address_space(3))) uint32_t*)(lp), 16, 0, 0)

// fp32 tile GEMM. part==null: C = act(A@B + bias). part!=null: raw partial
// for K-slice blockIdx.z into part + z*M*N (combine_act finishes it).
__global__ __launch_bounds__(256) void gemm_fp32(
    const float* __restrict__ A, const float* __restrict__ Bm,
    const float* __restrict__ bias, float* __restrict__ C,
    float* __restrict__ part,
    int M, int N, int Kd, int kLen, int act)
{
    __shared__ float As[TK][TM + 4];
    __shared__ float Bs[TK][140];     // 128 cols staggered: +4 words per 32
    const int tid = threadIdx.x;
    const int bm = blockIdx.y * TM;
    const int bn = blockIdx.x * TN;
    const int kStart = blockIdx.z * kLen;
    const int tx = tid & 15;
    const int ty = tid >> 4;

    const int arow = tid >> 2;
    const int acol = (tid & 3) << 2;
    const int brow = tid >> 5;
    const int bcol = (tid & 31) << 2;

    float acc[8][8];
#pragma unroll
    for (int i = 0; i < 8; i++)
#pragma unroll
        for (int j = 0; j < 8; j++) acc[i][j] = 0.f;

    const float* Ap0 = A + (size_t)(bm + arow) * Kd + acol;
    const float* Ap1 = A + (size_t)(bm + arow + 64) * Kd + acol;
    const float* Bp0 = Bm + (size_t)brow * N + bn + bcol;
    const float* Bp1 = Bm + (size_t)(brow + 8) * N + bn + bcol;

    const int pb0 = bsw(bcol);            // staggered store offsets
    const int prb0 = bsw(tx * 8);         // staggered read offsets
    const int prb1 = prb0 + 4;            // tx*8+4 stays in same 32-group

    for (int k0 = kStart; k0 < kStart + kLen; k0 += TK) {
        const float4 a0 = *(const float4*)(Ap0 + k0);
        const float4 a1 = *(const float4*)(Ap1 + k0);
        const float4 b0 = *(const float4*)(Bp0 + (size_t)k0 * N);
        const float4 b1 = *(const float4*)(Bp1 + (size_t)k0 * N);
        __syncthreads();
        As[acol + 0][arow] = a0.x; As[acol + 1][arow] = a0.y;
        As[acol + 2][arow] = a0.z; As[acol + 3][arow] = a0.w;
        As[acol + 0][arow + 64] = a1.x; As[acol + 1][arow + 64] = a1.y;
        As[acol + 2][arow + 64] = a1.z; As[acol + 3][arow + 64] = a1.w;
        *(float4*)&Bs[brow][pb0]     = b0;
        *(float4*)&Bs[brow + 8][pb0] = b1;
        __syncthreads();
#pragma unroll
        for (int kk = 0; kk < TK; kk++) {
            float a[8], b[8];
            *(float4*)&a[0] = *(const float4*)&As[kk][ty * 8];
            *(float4*)&a[4] = *(const float4*)&As[kk][ty * 8 + 4];
            *(float4*)&b[0] = *(const float4*)&Bs[kk][prb0];
            *(float4*)&b[4] = *(const float4*)&Bs[kk][prb1];
#pragma unroll
            for (int i = 0; i < 8; i++)
#pragma unroll
                for (int j = 0; j < 8; j++)
                    acc[i][j] = fmaf(a[i], b[j], acc[i][j]);
        }
    }

    if (part) {
        float* P = part + (size_t)blockIdx.z * M * N;
#pragma unroll
        for (int i = 0; i < 8; i++) {
            const int row = bm + ty * 8 + i;
            *(float4*)&P[(size_t)row * N + bn + tx * 8]     = *(float4*)&acc[i][0];
            *(float4*)&P[(size_t)row * N + bn + tx * 8 + 4] = *(float4*)&acc[i][4];
        }
        return;
    }

    float bv[8];
#pragma unroll
    for (int j = 0; j < 8; j++) bv[j] = bias[bn + tx * 8 + j];
#pragma unroll
    for (int i = 0; i < 8; i++) {
        const int row = bm + ty * 8 + i;
        float o[8];
#pragma unroll
        for (int j = 0; j < 8; j++) {
            float v = acc[i][j] + bv[j];
            if (act == 0) v = (v > 0.f) ? v : 0.01f * v;
            else          v = 1.0f / (1.0f + __expf(-v));
            o[j] = v;
        }
        *(float4*)&C[(size_t)row * N + bn + tx * 8]     = *(float4*)&o[0];
        *(float4*)&C[(size_t)row * N + bn + tx * 8 + 4] = *(float4*)&o[4];
    }
}

// sum S split-K partials + bias + leaky; write fp32 or bf16
__global__ __launch_bounds__(256) void combine_act(
    const float* __restrict__ part, int S, size_t MN,
    const float* __restrict__ bias, int N,
    float* __restrict__ outF, unsigned short* __restrict__ outB)
{
    const size_t e = ((size_t)blockIdx.x * 256 + threadIdx.x) * 4;
    if (e >= MN) return;
    float4 s = *(const float4*)(part + e);
    for (int i = 1; i < S; i++) {
        const float4 p = *(const float4*)(part + (size_t)i * MN + e);
        s.x += p.x; s.y += p.y; s.z += p.z; s.w += p.w;
    }
    const int col = (int)(e & (size_t)(N - 1));
    const float4 bv = *(const float4*)(bias + col);
    float v0 = s.x + bv.x, v1 = s.y + bv.y, v2 = s.z + bv.z, v3 = s.w + bv.w;
    v0 = (v0 > 0.f) ? v0 : 0.01f * v0;
    v1 = (v1 > 0.f) ? v1 : 0.01f * v1;
    v2 = (v2 > 0.f) ? v2 : 0.01f * v2;
    v3 = (v3 > 0.f) ? v3 : 0.01f * v3;
    if (outF) {
        float4 o; o.x = v0; o.y = v1; o.z = v2; o.w = v3;
        *(float4*)(outF + e) = o;
    } else {
        ushort4 o; o.x = f2bf(v0); o.y = f2bf(v1); o.z = f2bf(v2); o.w = f2bf(v3);
        *(ushort4*)(outB + e) = o;
    }
}

// WT[c][r] = bf16(W[r][c]); W is R x Cc
__global__ __launch_bounds__(256) void transpose_cast(
    const float* __restrict__ W, unsigned short* __restrict__ WT, int R, int Cc)
{
    __shared__ float s[32][33];
    const int tx = threadIdx.x & 31, ty = threadIdx.x >> 5;
    const int c0 = blockIdx.x * 32, r0 = blockIdx.y * 32;
#pragma unroll
    for (int i = 0; i < 4; i++)
        s[ty + i * 8][tx] = W[(size_t)(r0 + ty + i * 8) * Cc + c0 + tx];
    __syncthreads();
#pragma unroll
    for (int i = 0; i < 4; i++)
        WT[(size_t)(c0 + ty + i * 8) * R + r0 + tx] = f2bf(s[tx][ty + i * 8]);
}

// Th/Tl[c][r] = fp16 hi/lo split of W[r][c] (lo scaled by 2^12); W is R x Cc
__global__ __launch_bounds__(256) void transpose_split_f16(
    const float* __restrict__ W, unsigned short* __restrict__ Th,
    unsigned short* __restrict__ Tl, int R, int Cc)
{
    __shared__ float s[32][33];
    const int tx = threadIdx.x & 31, ty = threadIdx.x >> 5;
    const int c0 = blockIdx.x * 32, r0 = blockIdx.y * 32;
#pragma unroll
    for (int i = 0; i < 4; i++)
        s[ty + i * 8][tx] = W[(size_t)(r0 + ty + i * 8) * Cc + c0 + tx];
    __syncthreads();
#pragma unroll
    for (int i = 0; i < 4; i++) {
        const float f = s[tx][ty + i * 8];
        const _Float16 h = (_Float16)f;
        const float fh = (float)h;
        const _Float16 lo = (_Float16)((f - fh) * 4096.0f);
        union { _Float16 hf; unsigned short u; } ch, cl;
        ch.hf = h; cl.hf = lo;
        Th[(size_t)(c0 + ty + i * 8) * R + r0 + tx] = ch.u;
        Tl[(size_t)(c0 + ty + i * 8) * R + r0 + tx] = cl.u;
    }
}

// ---------------- enc1: fp16x2-split MFMA -----------------------------------
// C_partial[z] = x @ We1 (K-slice z), fp32-accurate via Dekker fp16 split:
//   x = xh + xl/4096, w = wh + wl/4096
//   C = (xh@wh) + 2^-12 * (xh@wl + xl@wh)        (lo*lo ~2^-24, omitted)
// BM=64 BN=256(full N: x read once) BK=32, split-K=2, 4 waves, dbuf LDS 80KB.
// 2 blocks/CU: cross-block wave overlap covers barrier drains (m97 mechanism).
// B staging: wave w stages its OWN 4 col t-blocks (4w..4w+3) -> LDS slot s
// holds global t-block s (dest offsets bfrB + t*512, in-bounds by design).
__global__ __launch_bounds__(256, 2) void gemm_f16x2_enc1(
    const float* __restrict__ X,             // 16384 x 4096 f32
    const unsigned short* __restrict__ Bh,   // 256 x 4096 f16 (We1^T hi)
    const unsigned short* __restrict__ Bl,   // 256 x 4096 f16 (We1^T lo*2^12)
    float* __restrict__ part)                // [2][16384][256] f32
{
    __shared__ short Ah[2][2048];    // 4 t-blocks (64 rows) frag-order, 8 KB
    __shared__ short Al[2][2048];
    __shared__ short Bhs[2][8192];   // 16 t-blocks (256 cols), 32 KB
    __shared__ short Bls[2][8192];
    const int tid = threadIdx.x;
    const int l = tid & 63, w = tid >> 6;     // 4 waves; wave w -> cols w*64
    const int lm = l & 15, lq = l >> 4;
    const int bm = blockIdx.y * 64;
    const int kStart = blockIdx.z * 2048;

    // A staging: wave w owns row t-block w (rows w*16+lm), lane k-oct = lq
    const float* gA = X + (size_t)(bm + w * 16 + lm) * 4096 + kStart + lq * 8;
    // B staging: wave w owns col t-blocks 4w..4w+3 (rows w*64 + t*16 of We1^T)
    const unsigned short* gBh0 = Bh + (size_t)(w * 64 + lm) * 4096 + kStart + lq * 8;
    const unsigned short* gBl0 = Bl + (size_t)(w * 64 + lm) * 4096 + kStart + lq * 8;
    const size_t rstep = (size_t)16 * 4096;   // next t-block (16 global rows)

    const int aoff = (w << 9) + (l << 3);     // A store slot (shorts)
    const int fr0 = (lq << 7) + (lm << 3);    // frag lane offset
    const int bfrB = (w << 11);               // wave's B t-block base (4w*512)

    f32x4 acc1[4][4], acc2[4][4];
#pragma unroll
    for (int i = 0; i < 4; i++)
#pragma unroll
        for (int j = 0; j < 4; j++) {
            acc1[i][j] = (f32x4){0.f, 0.f, 0.f, 0.f};
            acc2[i][j] = (f32x4){0.f, 0.f, 0.f, 0.f};
        }

    // prologue: stage buf0 (k=0)
    {
        float fv[8];
        *(float4*)&fv[0] = *(const float4*)(gA);
        *(float4*)&fv[4] = *(const float4*)(gA + 4);
        GLL16(gBh0,             &Bhs[0][bfrB]);
        GLL16(gBh0 + rstep,     &Bhs[0][bfrB + 512]);
        GLL16(gBh0 + 2 * rstep, &Bhs[0][bfrB + 1024]);
        GLL16(gBh0 + 3 * rstep, &Bhs[0][bfrB + 1536]);
        GLL16(gBl0,             &Bls[0][bfrB]);
        GLL16(gBl0 + rstep,     &Bls[0][bfrB + 512]);
        GLL16(gBl0 + 2 * rstep, &Bls[0][bfrB + 1024]);
        GLL16(gBl0 + 3 * rstep, &Bls[0][bfrB + 1536]);
        union { _Float16 h[8]; short8 s; } uh, ul;
#pragma unroll
        for (int e = 0; e < 8; e++) {
            const float f = fv[e];
            const _Float16 h = (_Float16)f;
            const float fh = (float)h;
            uh.h[e] = h;
            ul.h[e] = (_Float16)((f - fh) * 4096.0f);
        }
        *(short8*)&Ah[0][aoff] = uh.s;
        *(short8*)&Al[0][aoff] = ul.s;
    }

    for (int k0 = 0; k0 < 2048; k0 += 32) {
        const int buf = (k0 >> 5) & 1;
        const int nb = buf ^ 1;
        const int kn = k0 + 32;
        __syncthreads();   // stage(buf) complete (vmcnt+lgkm drained)
        float4 a0, a1;
        if (kn < 2048) {
            // A fp32 loads FIRST (oldest in vmcnt FIFO): the convert below
            // waits vmcnt(8), leaving the 8 GLLs in flight until the barrier.
            a0 = *(const float4*)(gA + kn);
            a1 = *(const float4*)(gA + kn + 4);
            GLL16(gBh0 + kn,             &Bhs[nb][bfrB]);
            GLL16(gBh0 + kn + rstep,     &Bhs[nb][bfrB + 512]);
            GLL16(gBh0 + kn + 2 * rstep, &Bhs[nb][bfrB + 1024]);
            GLL16(gBh0 + kn + 3 * rstep, &Bhs[nb][bfrB + 1536]);
            GLL16(gBl0 + kn,             &Bls[nb][bfrB]);
            GLL16(gBl0 + kn + rstep,     &Bls[nb][bfrB + 512]);
            GLL16(gBl0 + kn + 2 * rstep, &Bls[nb][bfrB + 1024]);
            GLL16(gBl0 + kn + 3 * rstep, &Bls[nb][bfrB + 1536]);
        }
        half8 ah[4], bh[4];
#pragma unroll
        for (int i = 0; i < 4; i++)
            ah[i] = *(const half8*)&Ah[buf][(i << 9) + fr0];
#pragma unroll
        for (int j = 0; j < 4; j++)
            bh[j] = *(const half8*)&Bhs[buf][bfrB + (j << 9) + fr0];
#pragma unroll
        for (int i = 0; i < 4; i++)
#pragma unroll
            for (int j = 0; j < 4; j++)
                acc1[i][j] = __builtin_amdgcn_mfma_f32_16x16x32_f16(
                    ah[i], bh[j], acc1[i][j], 0, 0, 0);
        half8 bl[4];
#pragma unroll
        for (int j = 0; j < 4; j++)
            bl[j] = *(const half8*)&Bls[buf][bfrB + (j << 9) + fr0];
#pragma unroll
        for (int i = 0; i < 4; i++)
#pragma unroll
            for (int j = 0; j < 4; j++)
                acc2[i][j] = __builtin_amdgcn_mfma_f32_16x16x32_f16(
                    ah[i], bl[j], acc2[i][j], 0, 0, 0);
        half8 al[4];
#pragma unroll
        for (int i = 0; i < 4; i++)
            al[i] = *(const half8*)&Al[buf][(i << 9) + fr0];
#pragma unroll
        for (int i = 0; i < 4; i++)
#pragma unroll
            for (int j = 0; j < 4; j++)
                acc2[i][j] = __builtin_amdgcn_mfma_f32_16x16x32_f16(
                    al[i], bh[j], acc2[i][j], 0, 0, 0);
        if (kn < 2048) {   // convert+write AFTER MFMAs: load latency covered
            float fv[8];
            *(float4*)&fv[0] = a0;
            *(float4*)&fv[4] = a1;
            union { _Float16 h[8]; short8 s; } uh, ul;
#pragma unroll
            for (int e = 0; e < 8; e++) {
                const float f = fv[e];
                const _Float16 h = (_Float16)f;
                const float fh = (float)h;
                uh.h[e] = h;
                ul.h[e] = (_Float16)((f - fh) * 4096.0f);
            }
            *(short8*)&Ah[nb][aoff] = uh.s;
            *(short8*)&Al[nb][aoff] = ul.s;
        }
    }

    float* P = part + (size_t)blockIdx.z * BB * 256;
    const float inv = 0.000244140625f;   // 2^-12
#pragma unroll
    for (int i = 0; i < 4; i++)
#pragma unroll
        for (int j = 0; j < 4; j++) {
            const int col = w * 64 + j * 16 + lm;
#pragma unroll
            for (int r = 0; r < 4; r++) {
                const int row = bm + i * 16 + lq * 4 + r;
                P[(size_t)row * 256 + col] = acc1[i][j][r] + inv * acc2[i][j][r];
            }
        }
}

// ---------------- dec3: bf16 MFMA, X = sigmoid(Ag @ WT^T + bias) ------------
__global__ __launch_bounds__(256) void gemm_bf16_dec3(
    const unsigned short* __restrict__ Ag,   // 16384 x 256 bf16 row-major
    const unsigned short* __restrict__ Bt,   // 4096 x 256 bf16 row-major (Wd3^T)
    const float* __restrict__ bias, float* __restrict__ C)
{
    // frag-order LDS: t-block (16 rows) x quad x lane -> contiguous 16B slots
    __shared__ short As[4096];   // 8 KB: 8 t-blocks x 512 shorts
    __shared__ short Bs2[4096];
    const int tid = threadIdx.x;
    const int l = tid & 63, w = tid >> 6;
    const int lm = l & 15, lq = l >> 4;
    const int bm = blockIdx.y * 128, bn = blockIdx.x * 128;
    const int wm = (w >> 1) * 64, wn = (w & 1) * 64;

    const int t0 = w * 2, t1 = w * 2 + 1;   // staging t-blocks for this wave
    const unsigned short* ga0 = Ag + (size_t)(bm + t0 * 16 + lm) * 256 + lq * 8;
    const unsigned short* ga1 = Ag + (size_t)(bm + t1 * 16 + lm) * 256 + lq * 8;
    const unsigned short* gb0 = Bt + (size_t)(bn + t0 * 16 + lm) * 256 + lq * 8;
    const unsigned short* gb1 = Bt + (size_t)(bn + t1 * 16 + lm) * 256 + lq * 8;

    f32x4 acc[4][4];
#pragma unroll
    for (int i = 0; i < 4; i++)
#pragma unroll
        for (int j = 0; j < 4; j++) acc[i][j] = (f32x4){0.f, 0.f, 0.f, 0.f};

    for (int k0 = 0; k0 < 256; k0 += 32) {
        __syncthreads();   // previous iteration's reads done
        GLL16(ga0 + k0, &As[t0 * 512]);
        GLL16(ga1 + k0, &As[t1 * 512]);
        GLL16(gb0 + k0, &Bs2[t0 * 512]);
        GLL16(gb1 + k0, &Bs2[t1 * 512]);
        __syncthreads();   // drains vmcnt: staged data visible
        short8 af[4], bf[4];
#pragma unroll
        for (int i = 0; i < 4; i++)
            af[i] = *(const short8*)&As[((w >> 1) * 4 + i) * 512 + lq * 128 + lm * 8];
#pragma unroll
        for (int j = 0; j < 4; j++)
            bf[j] = *(const short8*)&Bs2[((w & 1) * 4 + j) * 512 + lq * 128 + lm * 8];
#pragma unroll
        for (int i = 0; i < 4; i++)
#pragma unroll
            for (int j = 0; j < 4; j++)
                acc[i][j] = __builtin_amdgcn_mfma_f32_16x16x32_bf16(
                    af[i], bf[j], acc[i][j], 0, 0, 0);
    }

#pragma unroll
    for (int i = 0; i < 4; i++) {
#pragma unroll
        for (int j = 0; j < 4; j++) {
            const int col = bn + wn + j * 16 + lm;
            const float bv = bias[col];
#pragma unroll
            for (int r = 0; r < 4; r++) {
                const int row = bm + wm + i * 16 + lq * 4 + r;
                float v = acc[i][j][r] + bv;
                v = 1.0f / (1.0f + __expf(-v));
                C[(size_t)row * 4096 + col] = v;
            }
        }
    }
}

// ---------------- VQ (unchanged fp32) ---------------------------------------
__global__ __launch_bounds__(512) void vq_argmin(
    const float* __restrict__ ze, const float* __restrict__ cb,
    float* __restrict__ idxf)
{
    __shared__ float cbs[64 * 512];
    __shared__ float As[64][68];
    __shared__ float w2s[512];
    const int tid = threadIdx.x;
    const int p0 = blockIdx.x * 64;

    const float4* cb4 = (const float4*)cb;
    float4* cbs4 = (float4*)cbs;
    for (int i = tid; i < 8192; i += 512) cbs4[i] = cb4[i];

    const float4* ze4 = (const float4*)(ze + (size_t)p0 * 64);
    for (int i = tid; i < 1024; i += 512) {
        float4 v = ze4[i];
        int e = i * 4;
        int bo = e >> 9, r = e & 511;
        int d = r >> 3, m = r & 7;
        *(float4*)&As[d][bo * 8 + m] = v;
    }
    __syncthreads();

    {
        float s = 0.f;
#pragma unroll
        for (int d = 0; d < 64; ++d) { float c = cbs[d * 512 + tid]; s = fmaf(c, c, s); }
        w2s[tid] = s;
    }
    __syncthreads();

    const int tx = tid & 63;
    const int ty = tid >> 6;

    float acc[8][8], x2a[8];
#pragma unroll
    for (int i = 0; i < 8; i++) {
        x2a[i] = 0.f;
#pragma unroll
        for (int j = 0; j < 8; j++) acc[i][j] = 0.f;
    }

#pragma unroll 8
    for (int kk = 0; kk < 64; ++kk) {
        float a[8], b[8];
        *(float4*)&a[0] = *(const float4*)&As[kk][ty * 8];
        *(float4*)&a[4] = *(const float4*)&As[kk][ty * 8 + 4];
        *(float4*)&b[0] = *(const float4*)&cbs[kk * 512 + tx * 8];
        *(float4*)&b[4] = *(const float4*)&cbs[kk * 512 + tx * 8 + 4];
#pragma unroll
        for (int i = 0; i < 8; i++) x2a[i] = fmaf(a[i], a[i], x2a[i]);
#pragma unroll
        for (int i = 0; i < 8; i++)
#pragma unroll
            for (int j = 0; j < 8; j++)
                acc[i][j] = fmaf(a[i], b[j], acc[i][j]);
    }

    float w2v[8];
#pragma unroll
    for (int j = 0; j < 8; j++) w2v[j] = w2s[tx * 8 + j];

#pragma unroll
    for (int i = 0; i < 8; i++) {
        float bd = 3.4e38f; int bk = 1 << 30;
#pragma unroll
        for (int j = 0; j < 8; j++) {
            float dsc = (x2a[i] - 2.0f * acc[i][j]) + w2v[j];
            if (dsc < bd) { bd = dsc; bk = tx * 8 + j; }
        }
        for (int off = 32; off > 0; off >>= 1) {
            float od = __shfl_xor(bd, off);
            int   ok = __shfl_xor(bk, off);
            if (od < bd || (od == bd && ok < bk)) { bd = od; bk = ok; }
        }
        if (tx == i) idxf[p0 + ty * 8 + i] = (float)bk;
    }
}

__global__ __launch_bounds__(256) void vq_gather(
    const float* __restrict__ ze, const float* __restrict__ idxf,
    const float* __restrict__ cb,
    float* __restrict__ zq, float* __restrict__ emb)
{
    const int t = blockIdx.x * 256 + threadIdx.x;
    const int e = t * 4;
    const int b = e >> 9, r = e & 511;
    const int d = r >> 3, m = r & 7;
    const float4 z = *(const float4*)(ze + e);
    float q[4];
#pragma unroll
    for (int c = 0; c < 4; c++) {
        int k = (int)idxf[b * 8 + m + c];
        q[c] = cb[d * 512 + k];
    }
    float4 zq4, em4;
    zq4.x = z.x + (q[0] - z.x); zq4.y = z.y + (q[1] - z.y);
    zq4.z = z.z + (q[2] - z.z); zq4.w = z.w + (q[3] - z.w);
    em4.x = q[0]; em4.y = q[1]; em4.z = q[2]; em4.w = q[3];
    *(float4*)(zq + e) = zq4;
    *(float4*)(emb + e) = em4;
}

extern "C" void kernel_launch(void* const* d_in, const int* in_sizes, int n_in,
                              void* d_out, int out_size, void* d_ws, size_t ws_size,
                              hipStream_t stream)
{
    const float* x   = (const float*)d_in[0];
    const float* We1 = (const float*)d_in[1];
    const float* be1 = (const float*)d_in[2];
    const float* We2 = (const float*)d_in[3];
    const float* be2 = (const float*)d_in[4];
    const float* We3 = (const float*)d_in[5];
    const float* be3 = (const float*)d_in[6];
    const float* Wd1 = (const float*)d_in[7];
    const float* bd1 = (const float*)d_in[8];
    const float* Wd2 = (const float*)d_in[9];
    const float* bd2 = (const float*)d_in[10];
    const float* Wd3 = (const float*)d_in[11];
    const float* bd3 = (const float*)d_in[12];
    const float* cb  = (const float*)d_in[13];

    float* out   = (float*)d_out;
    float* o_idx = out;
    float* o_ze  = o_idx + 131072;
    float* o_zq  = o_ze + 8388608;
    float* o_emb = o_zq + 8388608;
    float* o_X   = o_emb + 8388608;   // 268 MB; doubles as split-K scratch

    float* h1 = (float*)d_ws;                          // B*256 f32
    float* h2 = h1 + (size_t)BB * 256;                 // B*128 f32
    // decoder phase reuse (h1/h2 dead):
    float* g1 = h1;                                    // B*128 f32
    unsigned short* g2b = (unsigned short*)(h1 + (size_t)BB * 128); // B*256 bf16
    unsigned short* WT  = (unsigned short*)h2;         // 4096x256 bf16

    // We1^T fp16 hi/lo in the high region of o_X (untouched until dec3;
    // split-K partials use only the first 8.4M floats of o_X)
    unsigned short* Bth = (unsigned short*)(o_X + 16777216);   // 2 MB
    unsigned short* Btl = Bth + 1048576;                       // 2 MB

    // encoder
    transpose_split_f16<<<dim3(8, 128), 256, 0, stream>>>(We1, Bth, Btl, 4096, 256);
    gemm_f16x2_enc1<<<dim3(1, 256, 2), 256, 0, stream>>>(x, Bth, Btl, o_X);
    combine_act<<<4096, 256, 0, stream>>>(o_X, 2, (size_t)BB * 256, be1, 256, h1, nullptr);
    gemm_fp32<<<dim3(1, 128, 2), 256, 0, stream>>>(
        h1, We2, nullptr, nullptr, o_X, BB, 128, 256, 128, 0);
    combine_act<<<2048, 256, 0, stream>>>(o_X, 2, (size_t)BB * 128, be2, 128, h2, nullptr);
    gemm_fp32<<<dim3(4, 128, 1), 256, 0, stream>>>(
        h2, We3, be3, o_ze, nullptr, BB, 512, 128, 128, 0);

    // VQ
    vq_argmin<<<dim3(2048), dim3(512), 0, stream>>>(o_ze, cb, o_idx);
    vq_gather<<<dim3(8192), dim3(256), 0, stream>>>(o_ze, o_idx, cb, o_zq, o_emb);

    // Wd3^T cast (h2 dead after enc3)
    transpose_cast<<<dim3(128, 8), 256, 0, stream>>>(Wd3, WT, 256, 4096);

    // decoder
    gemm_fp32<<<dim3(1, 128, 4), 256, 0, stream>>>(
        o_zq, Wd1, nullptr, nullptr, o_X, BB, 128, 512, 128, 0);
    combine_act<<<2048, 256, 0, stream>>>(o_X, 4, (size_t)BB * 128, bd1, 128, g1, nullptr);
    gemm_fp32<<<dim3(2, 128, 2), 256, 0, stream>>>(
        g1, Wd2, nullptr, nullptr, o_X, BB, 256, 128, 64, 0);
    combine_act<<<4096, 256, 0, stream>>>(o_X, 2, (size_t)BB * 256, bd2, 256, nullptr, g2b);
    gemm_bf16_dec3<<<dim3(32, 128), 256, 0, stream>>>(g2b, WT, bd3, o_X);
}

// Round 5
// 1079.507 us; speedup vs baseline: 1.0147x; 1.0147x over previous
//
#include <hip/hip_runtime.h>
#include <cstdint>
#include <cstddef>

// ---------------------------------------------------------------------------
// VQ-VAE forward. B=16384 F=4096 H=512 D=64 M=8 K=512
// Out (floats): [idx 131072][z_e 8388608][z_q 8388608][emb 8388608][X 67108864]
// enc1 in fp16x2-split MFMA (Dekker split: fp32-accurate, argmin-safe).
//   BM=64 BN=256 BK=32, 4 waves. B-frags are per-wave-private -> loaded
//   straight to VGPRs (no LDS, no barrier drain). LDS only stages A (16 KB).
// enc2/enc3/dec1/dec2 fp32 (small). dec3 in bf16 MFMA (sigmoid tail).
// Split-K partials staged in o_X (written last by dec3).
// ws (25.2 MB): h1 | h2 ; decoder phase reuses: g1 | g2b(bf16) | WT(bf16)
// We1^T fp16 hi/lo lives in the high region of o_X (dead until dec3).
// ---------------------------------------------------------------------------

static constexpr int BB = 16384;
static constexpr int TM = 128, TN = 128, TK = 16;

typedef __attribute__((ext_vector_type(8))) short short8;
typedef __attribute__((ext_vector_type(8))) _Float16 half8;
typedef __attribute__((ext_vector_type(4))) float f32x4;

__device__ __forceinline__ unsigned short f2bf(float f) {
    union { float f; uint32_t u; } v; v.f = f;
    uint32_t r = (v.u + 0x7FFFu + ((v.u >> 16) & 1u)) >> 16;
    return (unsigned short)r;
}

// staggered Bs column mapping: breaks the tx*8 4-way bank conflict
__device__ __forceinline__ int bsw(int c) { return c + ((c >> 5) << 2); }

#define GLL16(gp, lp) \
    __builtin_amdgcn_global_load_lds( \
        (const __attribute__((address_space(1))) uint32_t*)(gp), \
        (__attribute__((address_space(3))) uint32_t*)(lp), 16, 0, 0)

// fp32 tile GEMM. part==null: C = act(A@B + bias). part!=null: raw partial
// for K-slice blockIdx.z into part + z*M*N (combine_act finishes it).
__global__ __launch_bounds__(256) void gemm_fp32(
    const float* __restrict__ A, const float* __restrict__ Bm,
    const float* __restrict__ bias, float* __restrict__ C,
    float* __restrict__ part,
    int M, int N, int Kd, int kLen, int act)
{
    __shared__ float As[TK][TM + 4];
    __shared__ float Bs[TK][140];     // 128 cols staggered: +4 words per 32
    const int tid = threadIdx.x;
    const int bm = blockIdx.y * TM;
    const int bn = blockIdx.x * TN;
    const int kStart = blockIdx.z * kLen;
    const int tx = tid & 15;
    const int ty = tid >> 4;

    const int arow = tid >> 2;
    const int acol = (tid & 3) << 2;
    const int brow = tid >> 5;
    const int bcol = (tid & 31) << 2;

    float acc[8][8];
#pragma unroll
    for (int i = 0; i < 8; i++)
#pragma unroll
        for (int j = 0; j < 8; j++) acc[i][j] = 0.f;

    const float* Ap0 = A + (size_t)(bm + arow) * Kd + acol;
    const float* Ap1 = A + (size_t)(bm + arow + 64) * Kd + acol;
    const float* Bp0 = Bm + (size_t)brow * N + bn + bcol;
    const float* Bp1 = Bm + (size_t)(brow + 8) * N + bn + bcol;

    const int pb0 = bsw(bcol);            // staggered store offsets
    const int prb0 = bsw(tx * 8);         // staggered read offsets
    const int prb1 = prb0 + 4;            // tx*8+4 stays in same 32-group

    for (int k0 = kStart; k0 < kStart + kLen; k0 += TK) {
        const float4 a0 = *(const float4*)(Ap0 + k0);
        const float4 a1 = *(const float4*)(Ap1 + k0);
        const float4 b0 = *(const float4*)(Bp0 + (size_t)k0 * N);
        const float4 b1 = *(const float4*)(Bp1 + (size_t)k0 * N);
        __syncthreads();
        As[acol + 0][arow] = a0.x; As[acol + 1][arow] = a0.y;
        As[acol + 2][arow] = a0.z; As[acol + 3][arow] = a0.w;
        As[acol + 0][arow + 64] = a1.x; As[acol + 1][arow + 64] = a1.y;
        As[acol + 2][arow + 64] = a1.z; As[acol + 3][arow + 64] = a1.w;
        *(float4*)&Bs[brow][pb0]     = b0;
        *(float4*)&Bs[brow + 8][pb0] = b1;
        __syncthreads();
#pragma unroll
        for (int kk = 0; kk < TK; kk++) {
            float a[8], b[8];
            *(float4*)&a[0] = *(const float4*)&As[kk][ty * 8];
            *(float4*)&a[4] = *(const float4*)&As[kk][ty * 8 + 4];
            *(float4*)&b[0] = *(const float4*)&Bs[kk][prb0];
            *(float4*)&b[4] = *(const float4*)&Bs[kk][prb1];
#pragma unroll
            for (int i = 0; i < 8; i++)
#pragma unroll
                for (int j = 0; j < 8; j++)
                    acc[i][j] = fmaf(a[i], b[j], acc[i][j]);
        }
    }

    if (part) {
        float* P = part + (size_t)blockIdx.z * M * N;
#pragma unroll
        for (int i = 0; i < 8; i++) {
            const int row = bm + ty * 8 + i;
            *(float4*)&P[(size_t)row * N + bn + tx * 8]     = *(float4*)&acc[i][0];
            *(float4*)&P[(size_t)row * N + bn + tx * 8 + 4] = *(float4*)&acc[i][4];
        }
        return;
    }

    float bv[8];
#pragma unroll
    for (int j = 0; j < 8; j++) bv[j] = bias[bn + tx * 8 + j];
#pragma unroll
    for (int i = 0; i < 8; i++) {
        const int row = bm + ty * 8 + i;
        float o[8];
#pragma unroll
        for (int j = 0; j < 8; j++) {
            float v = acc[i][j] + bv[j];
            if (act == 0) v = (v > 0.f) ? v : 0.01f * v;
            else          v = 1.0f / (1.0f + __expf(-v));
            o[j] = v;
        }
        *(float4*)&C[(size_t)row * N + bn + tx * 8]     = *(float4*)&o[0];
        *(float4*)&C[(size_t)row * N + bn + tx * 8 + 4] = *(float4*)&o[4];
    }
}

// sum S split-K partials + bias + leaky; write fp32 or bf16
__global__ __launch_bounds__(256) void combine_act(
    const float* __restrict__ part, int S, size_t MN,
    const float* __restrict__ bias, int N,
    float* __restrict__ outF, unsigned short* __restrict__ outB)
{
    const size_t e = ((size_t)blockIdx.x * 256 + threadIdx.x) * 4;
    if (e >= MN) return;
    float4 s = *(const float4*)(part + e);
    for (int i = 1; i < S; i++) {
        const float4 p = *(const float4*)(part + (size_t)i * MN + e);
        s.x += p.x; s.y += p.y; s.z += p.z; s.w += p.w;
    }
    const int col = (int)(e & (size_t)(N - 1));
    const float4 bv = *(const float4*)(bias + col);
    float v0 = s.x + bv.x, v1 = s.y + bv.y, v2 = s.z + bv.z, v3 = s.w + bv.w;
    v0 = (v0 > 0.f) ? v0 : 0.01f * v0;
    v1 = (v1 > 0.f) ? v1 : 0.01f * v1;
    v2 = (v2 > 0.f) ? v2 : 0.01f * v2;
    v3 = (v3 > 0.f) ? v3 : 0.01f * v3;
    if (outF) {
        float4 o; o.x = v0; o.y = v1; o.z = v2; o.w = v3;
        *(float4*)(outF + e) = o;
    } else {
        ushort4 o; o.x = f2bf(v0); o.y = f2bf(v1); o.z = f2bf(v2); o.w = f2bf(v3);
        *(ushort4*)(outB + e) = o;
    }
}

// WT[c][r] = bf16(W[r][c]); W is R x Cc
__global__ __launch_bounds__(256) void transpose_cast(
    const float* __restrict__ W, unsigned short* __restrict__ WT, int R, int Cc)
{
    __shared__ float s[32][33];
    const int tx = threadIdx.x & 31, ty = threadIdx.x >> 5;
    const int c0 = blockIdx.x * 32, r0 = blockIdx.y * 32;
#pragma unroll
    for (int i = 0; i < 4; i++)
        s[ty + i * 8][tx] = W[(size_t)(r0 + ty + i * 8) * Cc + c0 + tx];
    __syncthreads();
#pragma unroll
    for (int i = 0; i < 4; i++)
        WT[(size_t)(c0 + ty + i * 8) * R + r0 + tx] = f2bf(s[tx][ty + i * 8]);
}

// Th/Tl[c][r] = fp16 hi/lo split of W[r][c] (lo scaled by 2^12); W is R x Cc
__global__ __launch_bounds__(256) void transpose_split_f16(
    const float* __restrict__ W, unsigned short* __restrict__ Th,
    unsigned short* __restrict__ Tl, int R, int Cc)
{
    __shared__ float s[32][33];
    const int tx = threadIdx.x & 31, ty = threadIdx.x >> 5;
    const int c0 = blockIdx.x * 32, r0 = blockIdx.y * 32;
#pragma unroll
    for (int i = 0; i < 4; i++)
        s[ty + i * 8][tx] = W[(size_t)(r0 + ty + i * 8) * Cc + c0 + tx];
    __syncthreads();
#pragma unroll
    for (int i = 0; i < 4; i++) {
        const float f = s[tx][ty + i * 8];
        const _Float16 h = (_Float16)f;
        const float fh = (float)h;
        const _Float16 lo = (_Float16)((f - fh) * 4096.0f);
        union { _Float16 hf; unsigned short u; } ch, cl;
        ch.hf = h; cl.hf = lo;
        Th[(size_t)(c0 + ty + i * 8) * R + r0 + tx] = ch.u;
        Tl[(size_t)(c0 + ty + i * 8) * R + r0 + tx] = cl.u;
    }
}

// ---------------- enc1: fp16x2-split MFMA -----------------------------------
// C_partial[z] = x @ We1 (K-slice z), fp32-accurate via Dekker fp16 split:
//   x = xh + xl/4096, w = wh + wl/4096
//   C = (xh@wh) + 2^-12 * (xh@wl + xl@wh)        (lo*lo ~2^-24, omitted)
// BM=64 BN=256(full N: x read once) BK=32, split-K=2, 4 waves.
// B frags are wave-private -> direct global->VGPR loads (B stays hot in L2,
// waits are per-wave progressive vmcnt, no barrier collectivization).
// LDS only holds the A hi/lo tiles (shared by all 4 waves), 16 KB dbuf.
// A fp32 loads are issued LAST (youngest in vmcnt FIFO) and nontemporal.
__global__ __launch_bounds__(256, 2) void gemm_f16x2_enc1(
    const float* __restrict__ X,             // 16384 x 4096 f32
    const unsigned short* __restrict__ Bh,   // 256 x 4096 f16 (We1^T hi)
    const unsigned short* __restrict__ Bl,   // 256 x 4096 f16 (We1^T lo*2^12)
    float* __restrict__ part)                // [2][16384][256] f32
{
    __shared__ short Ah[2][2048];    // 4 t-blocks (64 rows) frag-order, 8 KB
    __shared__ short Al[2][2048];
    const int tid = threadIdx.x;
    const int l = tid & 63, w = tid >> 6;     // 4 waves; wave w -> cols w*64
    const int lm = l & 15, lq = l >> 4;
    const int bm = blockIdx.y * 64;
    const int kStart = blockIdx.z * 2048;

    // A staging: wave w owns row t-block w (rows w*16+lm), lane k-oct = lq
    const float* gA = X + (size_t)(bm + w * 16 + lm) * 4096 + kStart + lq * 8;
    // B direct: frag j of wave w = rows w*64 + j*16 + lm of We1^T
    const unsigned short* gBh = Bh + (size_t)(w * 64 + lm) * 4096 + kStart + lq * 8;
    const unsigned short* gBl = Bl + (size_t)(w * 64 + lm) * 4096 + kStart + lq * 8;
    const size_t rstep = (size_t)16 * 4096;   // next t-block (16 rows)

    const int aoff = (w << 9) + (l << 3);     // A store slot (shorts)
    const int fr0 = (lq << 7) + (lm << 3);    // frag lane offset

    f32x4 acc1[4][4], acc2[4][4];
#pragma unroll
    for (int i = 0; i < 4; i++)
#pragma unroll
        for (int j = 0; j < 4; j++) {
            acc1[i][j] = (f32x4){0.f, 0.f, 0.f, 0.f};
            acc2[i][j] = (f32x4){0.f, 0.f, 0.f, 0.f};
        }

    // prologue: stage A buf0 (k=0)
    {
        float fv[8];
        *(f32x4*)&fv[0] = __builtin_nontemporal_load((const f32x4*)(gA));
        *(f32x4*)&fv[4] = __builtin_nontemporal_load((const f32x4*)(gA + 4));
        union { _Float16 h[8]; short8 s; } uh, ul;
#pragma unroll
        for (int e = 0; e < 8; e++) {
            const float f = fv[e];
            const _Float16 h = (_Float16)f;
            const float fh = (float)h;
            uh.h[e] = h;
            ul.h[e] = (_Float16)((f - fh) * 4096.0f);
        }
        *(short8*)&Ah[0][aoff] = uh.s;
        *(short8*)&Al[0][aoff] = ul.s;
    }

    for (int k0 = 0; k0 < 2048; k0 += 32) {
        const int buf = (k0 >> 5) & 1;
        const int nb = buf ^ 1;
        const int kn = k0 + 32;
        __syncthreads();   // A stage(buf) visible to all waves
        // B frags for this K-step: direct global->reg, L2-resident.
        // Issued FIRST so B waits (vmcnt) never imply waiting on the
        // younger HBM A-loads below.
        half8 bh[4], bl[4];
#pragma unroll
        for (int j = 0; j < 4; j++) {
            bh[j] = *(const half8*)(gBh + (size_t)j * rstep + k0);
            bl[j] = *(const half8*)(gBl + (size_t)j * rstep + k0);
        }
        f32x4 a0, a1;
        if (kn < 2048) {   // next A tile (HBM, nontemporal: don't evict B)
            a0 = __builtin_nontemporal_load((const f32x4*)(gA + kn));
            a1 = __builtin_nontemporal_load((const f32x4*)(gA + kn + 4));
        }
        half8 ah[4];
#pragma unroll
        for (int i = 0; i < 4; i++)
            ah[i] = *(const half8*)&Ah[buf][(i << 9) + fr0];
#pragma unroll
        for (int i = 0; i < 4; i++)
#pragma unroll
            for (int j = 0; j < 4; j++)
                acc1[i][j] = __builtin_amdgcn_mfma_f32_16x16x32_f16(
                    ah[i], bh[j], acc1[i][j], 0, 0, 0);
#pragma unroll
        for (int i = 0; i < 4; i++)
#pragma unroll
            for (int j = 0; j < 4; j++)
                acc2[i][j] = __builtin_amdgcn_mfma_f32_16x16x32_f16(
                    ah[i], bl[j], acc2[i][j], 0, 0, 0);
        half8 al[4];
#pragma unroll
        for (int i = 0; i < 4; i++)
            al[i] = *(const half8*)&Al[buf][(i << 9) + fr0];
#pragma unroll
        for (int i = 0; i < 4; i++)
#pragma unroll
            for (int j = 0; j < 4; j++)
                acc2[i][j] = __builtin_amdgcn_mfma_f32_16x16x32_f16(
                    al[i], bh[j], acc2[i][j], 0, 0, 0);
        if (kn < 2048) {   // convert+write AFTER MFMAs: A latency covered
            float fv[8];
            *(f32x4*)&fv[0] = a0;
            *(f32x4*)&fv[4] = a1;
            union { _Float16 h[8]; short8 s; } uh, ul;
#pragma unroll
            for (int e = 0; e < 8; e++) {
                const float f = fv[e];
                const _Float16 h = (_Float16)f;
                const float fh = (float)h;
                uh.h[e] = h;
                ul.h[e] = (_Float16)((f - fh) * 4096.0f);
            }
            *(short8*)&Ah[nb][aoff] = uh.s;
            *(short8*)&Al[nb][aoff] = ul.s;
        }
    }

    float* P = part + (size_t)blockIdx.z * BB * 256;
    const float inv = 0.000244140625f;   // 2^-12
#pragma unroll
    for (int i = 0; i < 4; i++)
#pragma unroll
        for (int j = 0; j < 4; j++) {
            const int col = w * 64 + j * 16 + lm;
#pragma unroll
            for (int r = 0; r < 4; r++) {
                const int row = bm + i * 16 + lq * 4 + r;
                P[(size_t)row * 256 + col] = acc1[i][j][r] + inv * acc2[i][j][r];
            }
        }
}

// ---------------- dec3: bf16 MFMA, X = sigmoid(Ag @ WT^T + bias) ------------
__global__ __launch_bounds__(256) void gemm_bf16_dec3(
    const unsigned short* __restrict__ Ag,   // 16384 x 256 bf16 row-major
    const unsigned short* __restrict__ Bt,   // 4096 x 256 bf16 row-major (Wd3^T)
    const float* __restrict__ bias, float* __restrict__ C)
{
    // frag-order LDS: t-block (16 rows) x quad x lane -> contiguous 16B slots
    __shared__ short As[4096];   // 8 KB: 8 t-blocks x 512 shorts
    __shared__ short Bs2[4096];
    const int tid = threadIdx.x;
    const int l = tid & 63, w = tid >> 6;
    const int lm = l & 15, lq = l >> 4;
    const int bm = blockIdx.y * 128, bn = blockIdx.x * 128;
    const int wm = (w >> 1) * 64, wn = (w & 1) * 64;

    const int t0 = w * 2, t1 = w * 2 + 1;   // staging t-blocks for this wave
    const unsigned short* ga0 = Ag + (size_t)(bm + t0 * 16 + lm) * 256 + lq * 8;
    const unsigned short* ga1 = Ag + (size_t)(bm + t1 * 16 + lm) * 256 + lq * 8;
    const unsigned short* gb0 = Bt + (size_t)(bn + t0 * 16 + lm) * 256 + lq * 8;
    const unsigned short* gb1 = Bt + (size_t)(bn + t1 * 16 + lm) * 256 + lq * 8;

    f32x4 acc[4][4];
#pragma unroll
    for (int i = 0; i < 4; i++)
#pragma unroll
        for (int j = 0; j < 4; j++) acc[i][j] = (f32x4){0.f, 0.f, 0.f, 0.f};

    for (int k0 = 0; k0 < 256; k0 += 32) {
        __syncthreads();   // previous iteration's reads done
        GLL16(ga0 + k0, &As[t0 * 512]);
        GLL16(ga1 + k0, &As[t1 * 512]);
        GLL16(gb0 + k0, &Bs2[t0 * 512]);
        GLL16(gb1 + k0, &Bs2[t1 * 512]);
        __syncthreads();   // drains vmcnt: staged data visible
        short8 af[4], bf[4];
#pragma unroll
        for (int i = 0; i < 4; i++)
            af[i] = *(const short8*)&As[((w >> 1) * 4 + i) * 512 + lq * 128 + lm * 8];
#pragma unroll
        for (int j = 0; j < 4; j++)
            bf[j] = *(const short8*)&Bs2[((w & 1) * 4 + j) * 512 + lq * 128 + lm * 8];
#pragma unroll
        for (int i = 0; i < 4; i++)
#pragma unroll
            for (int j = 0; j < 4; j++)
                acc[i][j] = __builtin_amdgcn_mfma_f32_16x16x32_bf16(
                    af[i], bf[j], acc[i][j], 0, 0, 0);
    }

#pragma unroll
    for (int i = 0; i < 4; i++) {
#pragma unroll
        for (int j = 0; j < 4; j++) {
            const int col = bn + wn + j * 16 + lm;
            const float bv = bias[col];
#pragma unroll
            for (int r = 0; r < 4; r++) {
                const int row = bm + wm + i * 16 + lq * 4 + r;
                float v = acc[i][j][r] + bv;
                v = 1.0f / (1.0f + __expf(-v));
                C[(size_t)row * 4096 + col] = v;
            }
        }
    }
}

// ---------------- VQ (unchanged fp32) ---------------------------------------
__global__ __launch_bounds__(512) void vq_argmin(
    const float* __restrict__ ze, const float* __restrict__ cb,
    float* __restrict__ idxf)
{
    __shared__ float cbs[64 * 512];
    __shared__ float As[64][68];
    __shared__ float w2s[512];
    const int tid = threadIdx.x;
    const int p0 = blockIdx.x * 64;

    const float4* cb4 = (const float4*)cb;
    float4* cbs4 = (float4*)cbs;
    for (int i = tid; i < 8192; i += 512) cbs4[i] = cb4[i];

    const float4* ze4 = (const float4*)(ze + (size_t)p0 * 64);
    for (int i = tid; i < 1024; i += 512) {
        float4 v = ze4[i];
        int e = i * 4;
        int bo = e >> 9, r = e & 511;
        int d = r >> 3, m = r & 7;
        *(float4*)&As[d][bo * 8 + m] = v;
    }
    __syncthreads();

    {
        float s = 0.f;
#pragma unroll
        for (int d = 0; d < 64; ++d) { float c = cbs[d * 512 + tid]; s = fmaf(c, c, s); }
        w2s[tid] = s;
    }
    __syncthreads();

    const int tx = tid & 63;
    const int ty = tid >> 6;

    float acc[8][8], x2a[8];
#pragma unroll
    for (int i = 0; i < 8; i++) {
        x2a[i] = 0.f;
#pragma unroll
        for (int j = 0; j < 8; j++) acc[i][j] = 0.f;
    }

#pragma unroll 8
    for (int kk = 0; kk < 64; ++kk) {
        float a[8], b[8];
        *(float4*)&a[0] = *(const float4*)&As[kk][ty * 8];
        *(float4*)&a[4] = *(const float4*)&As[kk][ty * 8 + 4];
        *(float4*)&b[0] = *(const float4*)&cbs[kk * 512 + tx * 8];
        *(float4*)&b[4] = *(const float4*)&cbs[kk * 512 + tx * 8 + 4];
#pragma unroll
        for (int i = 0; i < 8; i++) x2a[i] = fmaf(a[i], a[i], x2a[i]);
#pragma unroll
        for (int i = 0; i < 8; i++)
#pragma unroll
            for (int j = 0; j < 8; j++)
                acc[i][j] = fmaf(a[i], b[j], acc[i][j]);
    }

    float w2v[8];
#pragma unroll
    for (int j = 0; j < 8; j++) w2v[j] = w2s[tx * 8 + j];

#pragma unroll
    for (int i = 0; i < 8; i++) {
        float bd = 3.4e38f; int bk = 1 << 30;
#pragma unroll
        for (int j = 0; j < 8; j++) {
            float dsc = (x2a[i] - 2.0f * acc[i][j]) + w2v[j];
            if (dsc < bd) { bd = dsc; bk = tx * 8 + j; }
        }
        for (int off = 32; off > 0; off >>= 1) {
            float od = __shfl_xor(bd, off);
            int   ok = __shfl_xor(bk, off);
            if (od < bd || (od == bd && ok < bk)) { bd = od; bk = ok; }
        }
        if (tx == i) idxf[p0 + ty * 8 + i] = (float)bk;
    }
}

__global__ __launch_bounds__(256) void vq_gather(
    const float* __restrict__ ze, const float* __restrict__ idxf,
    const float* __restrict__ cb,
    float* __restrict__ zq, float* __restrict__ emb)
{
    const int t = blockIdx.x * 256 + threadIdx.x;
    const int e = t * 4;
    const int b = e >> 9, r = e & 511;
    const int d = r >> 3, m = r & 7;
    const float4 z = *(const float4*)(ze + e);
    float q[4];
#pragma unroll
    for (int c = 0; c < 4; c++) {
        int k = (int)idxf[b * 8 + m + c];
        q[c] = cb[d * 512 + k];
    }
    float4 zq4, em4;
    zq4.x = z.x + (q[0] - z.x); zq4.y = z.y + (q[1] - z.y);
    zq4.z = z.z + (q[2] - z.z); zq4.w = z.w + (q[3] - z.w);
    em4.x = q[0]; em4.y = q[1]; em4.z = q[2]; em4.w = q[3];
    *(float4*)(zq + e) = zq4;
    *(float4*)(emb + e) = em4;
}

extern "C" void kernel_launch(void* const* d_in, const int* in_sizes, int n_in,
                              void* d_out, int out_size, void* d_ws, size_t ws_size,
                              hipStream_t stream)
{
    const float* x   = (const float*)d_in[0];
    const float* We1 = (const float*)d_in[1];
    const float* be1 = (const float*)d_in[2];
    const float* We2 = (const float*)d_in[3];
    const float* be2 = (const float*)d_in[4];
    const float* We3 = (const float*)d_in[5];
    const float* be3 = (const float*)d_in[6];
    const float* Wd1 = (const float*)d_in[7];
    const float* bd1 = (const float*)d_in[8];
    const float* Wd2 = (const float*)d_in[9];
    const float* bd2 = (const float*)d_in[10];
    const float* Wd3 = (const float*)d_in[11];
    const float* bd3 = (const float*)d_in[12];
    const float* cb  = (const float*)d_in[13];

    float* out   = (float*)d_out;
    float* o_idx = out;
    float* o_ze  = o_idx + 131072;
    float* o_zq  = o_ze + 8388608;
    float* o_emb = o_zq + 8388608;
    float* o_X   = o_emb + 8388608;   // 268 MB; doubles as split-K scratch

    float* h1 = (float*)d_ws;                          // B*256 f32
    float* h2 = h1 + (size_t)BB * 256;                 // B*128 f32
    // decoder phase reuse (h1/h2 dead):
    float* g1 = h1;                                    // B*128 f32
    unsigned short* g2b = (unsigned short*)(h1 + (size_t)BB * 128); // B*256 bf16
    unsigned short* WT  = (unsigned short*)h2;         // 4096x256 bf16

    // We1^T fp16 hi/lo in the high region of o_X (untouched until dec3;
    // split-K partials use only the first 8.4M floats of o_X)
    unsigned short* Bth = (unsigned short*)(o_X + 16777216);   // 2 MB
    unsigned short* Btl = Bth + 1048576;                       // 2 MB

    // encoder
    transpose_split_f16<<<dim3(8, 128), 256, 0, stream>>>(We1, Bth, Btl, 4096, 256);
    gemm_f16x2_enc1<<<dim3(1, 256, 2), 256, 0, stream>>>(x, Bth, Btl, o_X);
    combine_act<<<4096, 256, 0, stream>>>(o_X, 2, (size_t)BB * 256, be1, 256, h1, nullptr);
    gemm_fp32<<<dim3(1, 128, 2), 256, 0, stream>>>(
        h1, We2, nullptr, nullptr, o_X, BB, 128, 256, 128, 0);
    combine_act<<<2048, 256, 0, stream>>>(o_X, 2, (size_t)BB * 128, be2, 128, h2, nullptr);
    gemm_fp32<<<dim3(4, 128, 1), 256, 0, stream>>>(
        h2, We3, be3, o_ze, nullptr, BB, 512, 128, 128, 0);

    // VQ
    vq_argmin<<<dim3(2048), dim3(512), 0, stream>>>(o_ze, cb, o_idx);
    vq_gather<<<dim3(8192), dim3(256), 0, stream>>>(o_ze, o_idx, cb, o_zq, o_emb);

    // Wd3^T cast (h2 dead after enc3)
    transpose_cast<<<dim3(128, 8), 256, 0, stream>>>(Wd3, WT, 256, 4096);

    // decoder
    gemm_fp32<<<dim3(1, 128, 4), 256, 0, stream>>>(
        o_zq, Wd1, nullptr, nullptr, o_X, BB, 128, 512, 128, 0);
    combine_act<<<2048, 256, 0, stream>>>(o_X, 4, (size_t)BB * 128, bd1, 128, g1, nullptr);
    gemm_fp32<<<dim3(2, 128, 2), 256, 0, stream>>>(
        g1, Wd2, nullptr, nullptr, o_X, BB, 256, 128, 64, 0);
    combine_act<<<4096, 256, 0, stream>>>(o_X, 2, (size_t)BB * 256, bd2, 256, nullptr, g2b);
    gemm_bf16_dec3<<<dim3(32, 128), 256, 0, stream>>>(g2b, WT, bd3, o_X);
}

// Round 6
// 1056.376 us; speedup vs baseline: 1.0369x; 1.0219x over previous
//
#include <hip/hip_runtime.h>
#include <cstdint>
#include <cstddef>

// ---------------------------------------------------------------------------
// VQ-VAE forward. B=16384 F=4096 H=512 D=64 M=8 K=512
// Out (floats): [idx 131072][z_e 8388608][z_q 8388608][emb 8388608][X 67108864]
// enc1 in fp16x2-split MFMA (Dekker split: fp32-accurate, argmin-safe).
//   BM=64 BN=256 BK=32, 4 waves. B-frags wave-private in VGPRs; B-hi
//   prefetched 1 step ahead (reg dbuf), A prefetched 2 steps ahead
//   (reg->convert->LDS pipeline). vmcnt never drains to 0 in-loop.
// enc2/enc3/dec1/dec2 fp32 (small). dec3 in bf16 MFMA (sigmoid tail).
// Split-K partials staged in o_X (written last by dec3).
// ws (25.2 MB): h1 | h2 ; decoder phase reuses: g1 | g2b(bf16) | WT(bf16)
// We1^T fp16 hi/lo lives in the high region of o_X (dead until dec3).
// ---------------------------------------------------------------------------

static constexpr int BB = 16384;
static constexpr int TM = 128, TN = 128, TK = 16;

typedef __attribute__((ext_vector_type(8))) short short8;
typedef __attribute__((ext_vector_type(8))) _Float16 half8;
typedef __attribute__((ext_vector_type(4))) float f32x4;

__device__ __forceinline__ unsigned short f2bf(float f) {
    union { float f; uint32_t u; } v; v.f = f;
    uint32_t r = (v.u + 0x7FFFu + ((v.u >> 16) & 1u)) >> 16;
    return (unsigned short)r;
}

// staggered Bs column mapping: breaks the tx*8 4-way bank conflict
__device__ __forceinline__ int bsw(int c) { return c + ((c >> 5) << 2); }

#define GLL16(gp, lp) \
    __builtin_amdgcn_global_load_lds( \
        (const __attribute__((address_space(1))) uint32_t*)(gp), \
        (__attribute__((address_space(3))) uint32_t*)(lp), 16, 0, 0)

// fp32 tile GEMM. part==null: C = act(A@B + bias). part!=null: raw partial
// for K-slice blockIdx.z into part + z*M*N (combine_act finishes it).
__global__ __launch_bounds__(256) void gemm_fp32(
    const float* __restrict__ A, const float* __restrict__ Bm,
    const float* __restrict__ bias, float* __restrict__ C,
    float* __restrict__ part,
    int M, int N, int Kd, int kLen, int act)
{
    __shared__ float As[TK][TM + 4];
    __shared__ float Bs[TK][140];     // 128 cols staggered: +4 words per 32
    const int tid = threadIdx.x;
    const int bm = blockIdx.y * TM;
    const int bn = blockIdx.x * TN;
    const int kStart = blockIdx.z * kLen;
    const int tx = tid & 15;
    const int ty = tid >> 4;

    const int arow = tid >> 2;
    const int acol = (tid & 3) << 2;
    const int brow = tid >> 5;
    const int bcol = (tid & 31) << 2;

    float acc[8][8];
#pragma unroll
    for (int i = 0; i < 8; i++)
#pragma unroll
        for (int j = 0; j < 8; j++) acc[i][j] = 0.f;

    const float* Ap0 = A + (size_t)(bm + arow) * Kd + acol;
    const float* Ap1 = A + (size_t)(bm + arow + 64) * Kd + acol;
    const float* Bp0 = Bm + (size_t)brow * N + bn + bcol;
    const float* Bp1 = Bm + (size_t)(brow + 8) * N + bn + bcol;

    const int pb0 = bsw(bcol);            // staggered store offsets
    const int prb0 = bsw(tx * 8);         // staggered read offsets
    const int prb1 = prb0 + 4;            // tx*8+4 stays in same 32-group

    for (int k0 = kStart; k0 < kStart + kLen; k0 += TK) {
        const float4 a0 = *(const float4*)(Ap0 + k0);
        const float4 a1 = *(const float4*)(Ap1 + k0);
        const float4 b0 = *(const float4*)(Bp0 + (size_t)k0 * N);
        const float4 b1 = *(const float4*)(Bp1 + (size_t)k0 * N);
        __syncthreads();
        As[acol + 0][arow] = a0.x; As[acol + 1][arow] = a0.y;
        As[acol + 2][arow] = a0.z; As[acol + 3][arow] = a0.w;
        As[acol + 0][arow + 64] = a1.x; As[acol + 1][arow + 64] = a1.y;
        As[acol + 2][arow + 64] = a1.z; As[acol + 3][arow + 64] = a1.w;
        *(float4*)&Bs[brow][pb0]     = b0;
        *(float4*)&Bs[brow + 8][pb0] = b1;
        __syncthreads();
#pragma unroll
        for (int kk = 0; kk < TK; kk++) {
            float a[8], b[8];
            *(float4*)&a[0] = *(const float4*)&As[kk][ty * 8];
            *(float4*)&a[4] = *(const float4*)&As[kk][ty * 8 + 4];
            *(float4*)&b[0] = *(const float4*)&Bs[kk][prb0];
            *(float4*)&b[4] = *(const float4*)&Bs[kk][prb1];
#pragma unroll
            for (int i = 0; i < 8; i++)
#pragma unroll
                for (int j = 0; j < 8; j++)
                    acc[i][j] = fmaf(a[i], b[j], acc[i][j]);
        }
    }

    if (part) {
        float* P = part + (size_t)blockIdx.z * M * N;
#pragma unroll
        for (int i = 0; i < 8; i++) {
            const int row = bm + ty * 8 + i;
            *(float4*)&P[(size_t)row * N + bn + tx * 8]     = *(float4*)&acc[i][0];
            *(float4*)&P[(size_t)row * N + bn + tx * 8 + 4] = *(float4*)&acc[i][4];
        }
        return;
    }

    float bv[8];
#pragma unroll
    for (int j = 0; j < 8; j++) bv[j] = bias[bn + tx * 8 + j];
#pragma unroll
    for (int i = 0; i < 8; i++) {
        const int row = bm + ty * 8 + i;
        float o[8];
#pragma unroll
        for (int j = 0; j < 8; j++) {
            float v = acc[i][j] + bv[j];
            if (act == 0) v = (v > 0.f) ? v : 0.01f * v;
            else          v = 1.0f / (1.0f + __expf(-v));
            o[j] = v;
        }
        *(float4*)&C[(size_t)row * N + bn + tx * 8]     = *(float4*)&o[0];
        *(float4*)&C[(size_t)row * N + bn + tx * 8 + 4] = *(float4*)&o[4];
    }
}

// sum S split-K partials + bias + leaky; write fp32 or bf16
__global__ __launch_bounds__(256) void combine_act(
    const float* __restrict__ part, int S, size_t MN,
    const float* __restrict__ bias, int N,
    float* __restrict__ outF, unsigned short* __restrict__ outB)
{
    const size_t e = ((size_t)blockIdx.x * 256 + threadIdx.x) * 4;
    if (e >= MN) return;
    float4 s = *(const float4*)(part + e);
    for (int i = 1; i < S; i++) {
        const float4 p = *(const float4*)(part + (size_t)i * MN + e);
        s.x += p.x; s.y += p.y; s.z += p.z; s.w += p.w;
    }
    const int col = (int)(e & (size_t)(N - 1));
    const float4 bv = *(const float4*)(bias + col);
    float v0 = s.x + bv.x, v1 = s.y + bv.y, v2 = s.z + bv.z, v3 = s.w + bv.w;
    v0 = (v0 > 0.f) ? v0 : 0.01f * v0;
    v1 = (v1 > 0.f) ? v1 : 0.01f * v1;
    v2 = (v2 > 0.f) ? v2 : 0.01f * v2;
    v3 = (v3 > 0.f) ? v3 : 0.01f * v3;
    if (outF) {
        float4 o; o.x = v0; o.y = v1; o.z = v2; o.w = v3;
        *(float4*)(outF + e) = o;
    } else {
        ushort4 o; o.x = f2bf(v0); o.y = f2bf(v1); o.z = f2bf(v2); o.w = f2bf(v3);
        *(ushort4*)(outB + e) = o;
    }
}

// WT[c][r] = bf16(W[r][c]); W is R x Cc
__global__ __launch_bounds__(256) void transpose_cast(
    const float* __restrict__ W, unsigned short* __restrict__ WT, int R, int Cc)
{
    __shared__ float s[32][33];
    const int tx = threadIdx.x & 31, ty = threadIdx.x >> 5;
    const int c0 = blockIdx.x * 32, r0 = blockIdx.y * 32;
#pragma unroll
    for (int i = 0; i < 4; i++)
        s[ty + i * 8][tx] = W[(size_t)(r0 + ty + i * 8) * Cc + c0 + tx];
    __syncthreads();
#pragma unroll
    for (int i = 0; i < 4; i++)
        WT[(size_t)(c0 + ty + i * 8) * R + r0 + tx] = f2bf(s[tx][ty + i * 8]);
}

// Th/Tl[c][r] = fp16 hi/lo split of W[r][c] (lo scaled by 2^12); W is R x Cc
__global__ __launch_bounds__(256) void transpose_split_f16(
    const float* __restrict__ W, unsigned short* __restrict__ Th,
    unsigned short* __restrict__ Tl, int R, int Cc)
{
    __shared__ float s[32][33];
    const int tx = threadIdx.x & 31, ty = threadIdx.x >> 5;
    const int c0 = blockIdx.x * 32, r0 = blockIdx.y * 32;
#pragma unroll
    for (int i = 0; i < 4; i++)
        s[ty + i * 8][tx] = W[(size_t)(r0 + ty + i * 8) * Cc + c0 + tx];
    __syncthreads();
#pragma unroll
    for (int i = 0; i < 4; i++) {
        const float f = s[tx][ty + i * 8];
        const _Float16 h = (_Float16)f;
        const float fh = (float)h;
        const _Float16 lo = (_Float16)((f - fh) * 4096.0f);
        union { _Float16 hf; unsigned short u; } ch, cl;
        ch.hf = h; cl.hf = lo;
        Th[(size_t)(c0 + ty + i * 8) * R + r0 + tx] = ch.u;
        Tl[(size_t)(c0 + ty + i * 8) * R + r0 + tx] = cl.u;
    }
}

// ---------------- enc1: fp16x2-split MFMA, software-pipelined ---------------
// C_partial[z] = x @ We1 (K-slice z), fp32-accurate via Dekker fp16 split:
//   x = xh + xl/4096, w = wh + wl/4096
//   C = (xh@wh) + 2^-12 * (xh@wl + xl@wh)        (lo*lo ~2^-24, omitted)
// Pipeline per step k: [bl(k) issue][bh(k+1) issue][A(k+2) issue]
//   -> MFMAs(k) with bh(k) prefetched last step (wait = counted vmcnt)
//   -> convert A(k+1) (regs since step k-1) -> LDS[other buf].
// No vmcnt(0) in the loop; no global stores in-loop so the barrier only
// drains lgkmcnt and prefetches stay in flight across it.
template<int BUF>
__device__ __forceinline__ void enc1_step(
    int K0,
    const float* __restrict__ gA,
    const unsigned short* __restrict__ gBh,
    const unsigned short* __restrict__ gBl,
    short (&Ah)[2][2048], short (&Al)[2][2048],
    half8 (&bhC)[4], half8 (&bhN)[4], half8 (&blS)[4],
    f32x4& p0, f32x4& p1,
    f32x4 (&acc1)[4][4], f32x4 (&acc2)[4][4],
    int aoff, int fr0)
{
    constexpr size_t rstep = (size_t)16 * 4096;   // next t-block (16 rows)
    const int kn1 = K0 + 32, kn2 = K0 + 64;
    __syncthreads();   // LDS[BUF] (written last step) visible
    // bl for THIS step: issued first (oldest of this step's batch)
#pragma unroll
    for (int j = 0; j < 4; j++)
        blS[j] = *(const half8*)(gBl + (size_t)j * rstep + K0);
    // bh for NEXT step: stays in flight across this step + the barrier
    if (kn1 < 2048) {
#pragma unroll
        for (int j = 0; j < 4; j++)
            bhN[j] = *(const half8*)(gBh + (size_t)j * rstep + kn1);
    }
    // A two steps ahead (HBM latency spans two steps); nontemporal
    f32x4 f0, f1;
    if (kn2 < 2048) {
        f0 = __builtin_nontemporal_load((const f32x4*)(gA + kn2));
        f1 = __builtin_nontemporal_load((const f32x4*)(gA + kn2 + 4));
    }
    half8 ah[4];
#pragma unroll
    for (int i = 0; i < 4; i++)
        ah[i] = *(const half8*)&Ah[BUF][(i << 9) + fr0];
#pragma unroll
    for (int i = 0; i < 4; i++)
#pragma unroll
        for (int j = 0; j < 4; j++)
            acc1[i][j] = __builtin_amdgcn_mfma_f32_16x16x32_f16(
                ah[i], bhC[j], acc1[i][j], 0, 0, 0);
#pragma unroll
    for (int i = 0; i < 4; i++)
#pragma unroll
        for (int j = 0; j < 4; j++)
            acc2[i][j] = __builtin_amdgcn_mfma_f32_16x16x32_f16(
                ah[i], blS[j], acc2[i][j], 0, 0, 0);
    half8 al[4];
#pragma unroll
    for (int i = 0; i < 4; i++)
        al[i] = *(const half8*)&Al[BUF][(i << 9) + fr0];
#pragma unroll
    for (int i = 0; i < 4; i++)
#pragma unroll
        for (int j = 0; j < 4; j++)
            acc2[i][j] = __builtin_amdgcn_mfma_f32_16x16x32_f16(
                al[i], bhC[j], acc2[i][j], 0, 0, 0);
    // convert A(K0+32) (in p0/p1 since last step; wait already implied by
    // the bl wait above) into the other LDS buffer for the next step
    if (kn1 < 2048) {
        float fv[8];
        *(f32x4*)&fv[0] = p0;
        *(f32x4*)&fv[4] = p1;
        union { _Float16 h[8]; short8 s; } uh, ul;
#pragma unroll
        for (int e = 0; e < 8; e++) {
            const float f = fv[e];
            const _Float16 h = (_Float16)f;
            const float fh = (float)h;
            uh.h[e] = h;
            ul.h[e] = (_Float16)((f - fh) * 4096.0f);
        }
        *(short8*)&Ah[BUF ^ 1][aoff] = uh.s;
        *(short8*)&Al[BUF ^ 1][aoff] = ul.s;
    }
    if (kn2 < 2048) { p0 = f0; p1 = f1; }
}

__global__ __launch_bounds__(256, 2) void gemm_f16x2_enc1(
    const float* __restrict__ X,             // 16384 x 4096 f32
    const unsigned short* __restrict__ Bh,   // 256 x 4096 f16 (We1^T hi)
    const unsigned short* __restrict__ Bl,   // 256 x 4096 f16 (We1^T lo*2^12)
    float* __restrict__ part)                // [2][16384][256] f32
{
    __shared__ short Ah[2][2048];    // 4 t-blocks (64 rows) frag-order, 8 KB
    __shared__ short Al[2][2048];
    const int tid = threadIdx.x;
    const int l = tid & 63, w = tid >> 6;     // 4 waves; wave w -> cols w*64
    const int lm = l & 15, lq = l >> 4;
    const int bm = blockIdx.y * 64;
    const int kStart = blockIdx.z * 2048;

    // A staging: wave w owns row t-block w (rows w*16+lm), lane k-oct = lq
    const float* gA = X + (size_t)(bm + w * 16 + lm) * 4096 + kStart + lq * 8;
    // B direct: frag j of wave w = rows w*64 + j*16 + lm of We1^T
    const unsigned short* gBh = Bh + (size_t)(w * 64 + lm) * 4096 + kStart + lq * 8;
    const unsigned short* gBl = Bl + (size_t)(w * 64 + lm) * 4096 + kStart + lq * 8;
    constexpr size_t rstep = (size_t)16 * 4096;

    const int aoff = (w << 9) + (l << 3);     // A store slot (shorts)
    const int fr0 = (lq << 7) + (lm << 3);    // frag lane offset

    f32x4 acc1[4][4], acc2[4][4];
#pragma unroll
    for (int i = 0; i < 4; i++)
#pragma unroll
        for (int j = 0; j < 4; j++) {
            acc1[i][j] = (f32x4){0.f, 0.f, 0.f, 0.f};
            acc2[i][j] = (f32x4){0.f, 0.f, 0.f, 0.f};
        }

    half8 bhA[4], bhB[4], blS[4];
    f32x4 p0, p1;

    // prologue: B(0) hi -> bhA; A(0) -> convert -> LDS[0]; A(1) -> p regs
    {
#pragma unroll
        for (int j = 0; j < 4; j++)
            bhA[j] = *(const half8*)(gBh + (size_t)j * rstep);
        f32x4 a0 = __builtin_nontemporal_load((const f32x4*)(gA));
        f32x4 a1 = __builtin_nontemporal_load((const f32x4*)(gA + 4));
        p0 = __builtin_nontemporal_load((const f32x4*)(gA + 32));
        p1 = __builtin_nontemporal_load((const f32x4*)(gA + 36));
        float fv[8];
        *(f32x4*)&fv[0] = a0;
        *(f32x4*)&fv[4] = a1;
        union { _Float16 h[8]; short8 s; } uh, ul;
#pragma unroll
        for (int e = 0; e < 8; e++) {
            const float f = fv[e];
            const _Float16 h = (_Float16)f;
            const float fh = (float)h;
            uh.h[e] = h;
            ul.h[e] = (_Float16)((f - fh) * 4096.0f);
        }
        *(short8*)&Ah[0][aoff] = uh.s;
        *(short8*)&Al[0][aoff] = ul.s;
    }

    for (int k2 = 0; k2 < 2048; k2 += 64) {
        enc1_step<0>(k2,      gA, gBh, gBl, Ah, Al, bhA, bhB, blS,
                     p0, p1, acc1, acc2, aoff, fr0);
        enc1_step<1>(k2 + 32, gA, gBh, gBl, Ah, Al, bhB, bhA, blS,
                     p0, p1, acc1, acc2, aoff, fr0);
    }

    float* P = part + (size_t)blockIdx.z * BB * 256;
    const float inv = 0.000244140625f;   // 2^-12
#pragma unroll
    for (int i = 0; i < 4; i++)
#pragma unroll
        for (int j = 0; j < 4; j++) {
            const int col = w * 64 + j * 16 + lm;
#pragma unroll
            for (int r = 0; r < 4; r++) {
                const int row = bm + i * 16 + lq * 4 + r;
                P[(size_t)row * 256 + col] = acc1[i][j][r] + inv * acc2[i][j][r];
            }
        }
}

// ---------------- dec3: bf16 MFMA, X = sigmoid(Ag @ WT^T + bias) ------------
__global__ __launch_bounds__(256) void gemm_bf16_dec3(
    const unsigned short* __restrict__ Ag,   // 16384 x 256 bf16 row-major
    const unsigned short* __restrict__ Bt,   // 4096 x 256 bf16 row-major (Wd3^T)
    const float* __restrict__ bias, float* __restrict__ C)
{
    // frag-order LDS: t-block (16 rows) x quad x lane -> contiguous 16B slots
    __shared__ short As[4096];   // 8 KB: 8 t-blocks x 512 shorts
    __shared__ short Bs2[4096];
    const int tid = threadIdx.x;
    const int l = tid & 63, w = tid >> 6;
    const int lm = l & 15, lq = l >> 4;
    const int bm = blockIdx.y * 128, bn = blockIdx.x * 128;
    const int wm = (w >> 1) * 64, wn = (w & 1) * 64;

    const int t0 = w * 2, t1 = w * 2 + 1;   // staging t-blocks for this wave
    const unsigned short* ga0 = Ag + (size_t)(bm + t0 * 16 + lm) * 256 + lq * 8;
    const unsigned short* ga1 = Ag + (size_t)(bm + t1 * 16 + lm) * 256 + lq * 8;
    const unsigned short* gb0 = Bt + (size_t)(bn + t0 * 16 + lm) * 256 + lq * 8;
    const unsigned short* gb1 = Bt + (size_t)(bn + t1 * 16 + lm) * 256 + lq * 8;

    f32x4 acc[4][4];
#pragma unroll
    for (int i = 0; i < 4; i++)
#pragma unroll
        for (int j = 0; j < 4; j++) acc[i][j] = (f32x4){0.f, 0.f, 0.f, 0.f};

    for (int k0 = 0; k0 < 256; k0 += 32) {
        __syncthreads();   // previous iteration's reads done
        GLL16(ga0 + k0, &As[t0 * 512]);
        GLL16(ga1 + k0, &As[t1 * 512]);
        GLL16(gb0 + k0, &Bs2[t0 * 512]);
        GLL16(gb1 + k0, &Bs2[t1 * 512]);
        __syncthreads();   // drains vmcnt: staged data visible
        short8 af[4], bf[4];
#pragma unroll
        for (int i = 0; i < 4; i++)
            af[i] = *(const short8*)&As[((w >> 1) * 4 + i) * 512 + lq * 128 + lm * 8];
#pragma unroll
        for (int j = 0; j < 4; j++)
            bf[j] = *(const short8*)&Bs2[((w & 1) * 4 + j) * 512 + lq * 128 + lm * 8];
#pragma unroll
        for (int i = 0; i < 4; i++)
#pragma unroll
            for (int j = 0; j < 4; j++)
                acc[i][j] = __builtin_amdgcn_mfma_f32_16x16x32_bf16(
                    af[i], bf[j], acc[i][j], 0, 0, 0);
    }

#pragma unroll
    for (int i = 0; i < 4; i++) {
#pragma unroll
        for (int j = 0; j < 4; j++) {
            const int col = bn + wn + j * 16 + lm;
            const float bv = bias[col];
#pragma unroll
            for (int r = 0; r < 4; r++) {
                const int row = bm + wm + i * 16 + lq * 4 + r;
                float v = acc[i][j][r] + bv;
                v = 1.0f / (1.0f + __expf(-v));
                C[(size_t)row * 4096 + col] = v;
            }
        }
    }
}

// ---------------- VQ (unchanged fp32) ---------------------------------------
__global__ __launch_bounds__(512) void vq_argmin(
    const float* __restrict__ ze, const float* __restrict__ cb,
    float* __restrict__ idxf)
{
    __shared__ float cbs[64 * 512];
    __shared__ float As[64][68];
    __shared__ float w2s[512];
    const int tid = threadIdx.x;
    const int p0 = blockIdx.x * 64;

    const float4* cb4 = (const float4*)cb;
    float4* cbs4 = (float4*)cbs;
    for (int i = tid; i < 8192; i += 512) cbs4[i] = cb4[i];

    const float4* ze4 = (const float4*)(ze + (size_t)p0 * 64);
    for (int i = tid; i < 1024; i += 512) {
        float4 v = ze4[i];
        int e = i * 4;
        int bo = e >> 9, r = e & 511;
        int d = r >> 3, m = r & 7;
        *(float4*)&As[d][bo * 8 + m] = v;
    }
    __syncthreads();

    {
        float s = 0.f;
#pragma unroll
        for (int d = 0; d < 64; ++d) { float c = cbs[d * 512 + tid]; s = fmaf(c, c, s); }
        w2s[tid] = s;
    }
    __syncthreads();

    const int tx = tid & 63;
    const int ty = tid >> 6;

    float acc[8][8], x2a[8];
#pragma unroll
    for (int i = 0; i < 8; i++) {
        x2a[i] = 0.f;
#pragma unroll
        for (int j = 0; j < 8; j++) acc[i][j] = 0.f;
    }

#pragma unroll 8
    for (int kk = 0; kk < 64; ++kk) {
        float a[8], b[8];
        *(float4*)&a[0] = *(const float4*)&As[kk][ty * 8];
        *(float4*)&a[4] = *(const float4*)&As[kk][ty * 8 + 4];
        *(float4*)&b[0] = *(const float4*)&cbs[kk * 512 + tx * 8];
        *(float4*)&b[4] = *(const float4*)&cbs[kk * 512 + tx * 8 + 4];
#pragma unroll
        for (int i = 0; i < 8; i++) x2a[i] = fmaf(a[i], a[i], x2a[i]);
#pragma unroll
        for (int i = 0; i < 8; i++)
#pragma unroll
            for (int j = 0; j < 8; j++)
                acc[i][j] = fmaf(a[i], b[j], acc[i][j]);
    }

    float w2v[8];
#pragma unroll
    for (int j = 0; j < 8; j++) w2v[j] = w2s[tx * 8 + j];

#pragma unroll
    for (int i = 0; i < 8; i++) {
        float bd = 3.4e38f; int bk = 1 << 30;
#pragma unroll
        for (int j = 0; j < 8; j++) {
            float dsc = (x2a[i] - 2.0f * acc[i][j]) + w2v[j];
            if (dsc < bd) { bd = dsc; bk = tx * 8 + j; }
        }
        for (int off = 32; off > 0; off >>= 1) {
            float od = __shfl_xor(bd, off);
            int   ok = __shfl_xor(bk, off);
            if (od < bd || (od == bd && ok < bk)) { bd = od; bk = ok; }
        }
        if (tx == i) idxf[p0 + ty * 8 + i] = (float)bk;
    }
}

__global__ __launch_bounds__(256) void vq_gather(
    const float* __restrict__ ze, const float* __restrict__ idxf,
    const float* __restrict__ cb,
    float* __restrict__ zq, float* __restrict__ emb)
{
    const int t = blockIdx.x * 256 + threadIdx.x;
    const int e = t * 4;
    const int b = e >> 9, r = e & 511;
    const int d = r >> 3, m = r & 7;
    const float4 z = *(const float4*)(ze + e);
    float q[4];
#pragma unroll
    for (int c = 0; c < 4; c++) {
        int k = (int)idxf[b * 8 + m + c];
        q[c] = cb[d * 512 + k];
    }
    float4 zq4, em4;
    zq4.x = z.x + (q[0] - z.x); zq4.y = z.y + (q[1] - z.y);
    zq4.z = z.z + (q[2] - z.z); zq4.w = z.w + (q[3] - z.w);
    em4.x = q[0]; em4.y = q[1]; em4.z = q[2]; em4.w = q[3];
    *(float4*)(zq + e) = zq4;
    *(float4*)(emb + e) = em4;
}

extern "C" void kernel_launch(void* const* d_in, const int* in_sizes, int n_in,
                              void* d_out, int out_size, void* d_ws, size_t ws_size,
                              hipStream_t stream)
{
    const float* x   = (const float*)d_in[0];
    const float* We1 = (const float*)d_in[1];
    const float* be1 = (const float*)d_in[2];
    const float* We2 = (const float*)d_in[3];
    const float* be2 = (const float*)d_in[4];
    const float* We3 = (const float*)d_in[5];
    const float* be3 = (const float*)d_in[6];
    const float* Wd1 = (const float*)d_in[7];
    const float* bd1 = (const float*)d_in[8];
    const float* Wd2 = (const float*)d_in[9];
    const float* bd2 = (const float*)d_in[10];
    const float* Wd3 = (const float*)d_in[11];
    const float* bd3 = (const float*)d_in[12];
    const float* cb  = (const float*)d_in[13];

    float* out   = (float*)d_out;
    float* o_idx = out;
    float* o_ze  = o_idx + 131072;
    float* o_zq  = o_ze + 8388608;
    float* o_emb = o_zq + 8388608;
    float* o_X   = o_emb + 8388608;   // 268 MB; doubles as split-K scratch

    float* h1 = (float*)d_ws;                          // B*256 f32
    float* h2 = h1 + (size_t)BB * 256;                 // B*128 f32
    // decoder phase reuse (h1/h2 dead):
    float* g1 = h1;                                    // B*128 f32
    unsigned short* g2b = (unsigned short*)(h1 + (size_t)BB * 128); // B*256 bf16
    unsigned short* WT  = (unsigned short*)h2;         // 4096x256 bf16

    // We1^T fp16 hi/lo in the high region of o_X (untouched until dec3;
    // split-K partials use only the first 8.4M floats of o_X)
    unsigned short* Bth = (unsigned short*)(o_X + 16777216);   // 2 MB
    unsigned short* Btl = Bth + 1048576;                       // 2 MB

    // encoder
    transpose_split_f16<<<dim3(8, 128), 256, 0, stream>>>(We1, Bth, Btl, 4096, 256);
    gemm_f16x2_enc1<<<dim3(1, 256, 2), 256, 0, stream>>>(x, Bth, Btl, o_X);
    combine_act<<<4096, 256, 0, stream>>>(o_X, 2, (size_t)BB * 256, be1, 256, h1, nullptr);
    gemm_fp32<<<dim3(1, 128, 2), 256, 0, stream>>>(
        h1, We2, nullptr, nullptr, o_X, BB, 128, 256, 128, 0);
    combine_act<<<2048, 256, 0, stream>>>(o_X, 2, (size_t)BB * 128, be2, 128, h2, nullptr);
    gemm_fp32<<<dim3(4, 128, 1), 256, 0, stream>>>(
        h2, We3, be3, o_ze, nullptr, BB, 512, 128, 128, 0);

    // VQ
    vq_argmin<<<dim3(2048), dim3(512), 0, stream>>>(o_ze, cb, o_idx);
    vq_gather<<<dim3(8192), dim3(256), 0, stream>>>(o_ze, o_idx, cb, o_zq, o_emb);

    // Wd3^T cast (h2 dead after enc3)
    transpose_cast<<<dim3(128, 8), 256, 0, stream>>>(Wd3, WT, 256, 4096);

    // decoder
    gemm_fp32<<<dim3(1, 128, 4), 256, 0, stream>>>(
        o_zq, Wd1, nullptr, nullptr, o_X, BB, 128, 512, 128, 0);
    combine_act<<<2048, 256, 0, stream>>>(o_X, 4, (size_t)BB * 128, bd1, 128, g1, nullptr);
    gemm_fp32<<<dim3(2, 128, 2), 256, 0, stream>>>(
        g1, Wd2, nullptr, nullptr, o_X, BB, 256, 128, 64, 0);
    combine_act<<<4096, 256, 0, stream>>>(o_X, 2, (size_t)BB * 256, bd2, 256, nullptr, g2b);
    gemm_bf16_dec3<<<dim3(32, 128), 256, 0, stream>>>(g2b, WT, bd3, o_X);
}

// Round 8
// 980.056 us; speedup vs baseline: 1.1176x; 1.0779x over previous
//
#include <hip/hip_runtime.h>
#include <cstdint>
#include <cstddef>

// ---------------------------------------------------------------------------
// VQ-VAE forward. B=16384 F=4096 H=512 D=64 M=8 K=512
// Out (floats): [idx 131072][z_e 8388608][z_q 8388608][emb 8388608][X 67108864]
// ALL MLP GEMMs in fp16x2-split MFMA (Dekker: fp32-accurate, argmin-safe):
//   enc1: BM=64 BN=256 split-K=2, pipelined (B-hi +1 step, A +2 steps).
//   enc2/enc3/dec1/dec2: gemm_f16x2_mid<NJ,KLEN,ACT>, no split-K, fused
//   bias+leaky epilogue (fp32 or bf16 out). dec3 bf16 MFMA (sigmoid tail).
// ws (25.2 MB): h1 | h2 ; decoder phase reuses: g1 | g2b(bf16) | WT(bf16)
// LIFETIME: WT lives in h2 -> transpose_cast(Wd3) MUST launch after enc3
// (h2's last reader), NOT at the top (round-7 bug: enc2 clobbered WT).
// All W^T fp16 hi/lo splits live in the high region of o_X (dead until dec3).
// ---------------------------------------------------------------------------

static constexpr int BB = 16384;

typedef __attribute__((ext_vector_type(8))) short short8;
typedef __attribute__((ext_vector_type(8))) _Float16 half8;
typedef __attribute__((ext_vector_type(4))) float f32x4;

__device__ __forceinline__ unsigned short f2bf(float f) {
    union { float f; uint32_t u; } v; v.f = f;
    uint32_t r = (v.u + 0x7FFFu + ((v.u >> 16) & 1u)) >> 16;
    return (unsigned short)r;
}

#define GLL16(gp, lp) \
    __builtin_amdgcn_global_load_lds( \
        (const __attribute__((address_space(1))) uint32_t*)(gp), \
        (__attribute__((address_space(3))) uint32_t*)(lp), 16, 0, 0)

// sum S split-K partials + bias + leaky; write fp32 or bf16
__global__ __launch_bounds__(256) void combine_act(
    const float* __restrict__ part, int S, size_t MN,
    const float* __restrict__ bias, int N,
    float* __restrict__ outF, unsigned short* __restrict__ outB)
{
    const size_t e = ((size_t)blockIdx.x * 256 + threadIdx.x) * 4;
    if (e >= MN) return;
    float4 s = *(const float4*)(part + e);
    for (int i = 1; i < S; i++) {
        const float4 p = *(const float4*)(part + (size_t)i * MN + e);
        s.x += p.x; s.y += p.y; s.z += p.z; s.w += p.w;
    }
    const int col = (int)(e & (size_t)(N - 1));
    const float4 bv = *(const float4*)(bias + col);
    float v0 = s.x + bv.x, v1 = s.y + bv.y, v2 = s.z + bv.z, v3 = s.w + bv.w;
    v0 = (v0 > 0.f) ? v0 : 0.01f * v0;
    v1 = (v1 > 0.f) ? v1 : 0.01f * v1;
    v2 = (v2 > 0.f) ? v2 : 0.01f * v2;
    v3 = (v3 > 0.f) ? v3 : 0.01f * v3;
    if (outF) {
        float4 o; o.x = v0; o.y = v1; o.z = v2; o.w = v3;
        *(float4*)(outF + e) = o;
    } else {
        ushort4 o; o.x = f2bf(v0); o.y = f2bf(v1); o.z = f2bf(v2); o.w = f2bf(v3);
        *(ushort4*)(outB + e) = o;
    }
}

// WT[c][r] = bf16(W[r][c]); W is R x Cc
__global__ __launch_bounds__(256) void transpose_cast(
    const float* __restrict__ W, unsigned short* __restrict__ WT, int R, int Cc)
{
    __shared__ float s[32][33];
    const int tx = threadIdx.x & 31, ty = threadIdx.x >> 5;
    const int c0 = blockIdx.x * 32, r0 = blockIdx.y * 32;
#pragma unroll
    for (int i = 0; i < 4; i++)
        s[ty + i * 8][tx] = W[(size_t)(r0 + ty + i * 8) * Cc + c0 + tx];
    __syncthreads();
#pragma unroll
    for (int i = 0; i < 4; i++)
        WT[(size_t)(c0 + ty + i * 8) * R + r0 + tx] = f2bf(s[tx][ty + i * 8]);
}

// Th/Tl[c][r] = fp16 hi/lo split of W[r][c] (lo scaled by 2^12); W is R x Cc
__global__ __launch_bounds__(256) void transpose_split_f16(
    const float* __restrict__ W, unsigned short* __restrict__ Th,
    unsigned short* __restrict__ Tl, int R, int Cc)
{
    __shared__ float s[32][33];
    const int tx = threadIdx.x & 31, ty = threadIdx.x >> 5;
    const int c0 = blockIdx.x * 32, r0 = blockIdx.y * 32;
#pragma unroll
    for (int i = 0; i < 4; i++)
        s[ty + i * 8][tx] = W[(size_t)(r0 + ty + i * 8) * Cc + c0 + tx];
    __syncthreads();
#pragma unroll
    for (int i = 0; i < 4; i++) {
        const float f = s[tx][ty + i * 8];
        const _Float16 h = (_Float16)f;
        const float fh = (float)h;
        const _Float16 lo = (_Float16)((f - fh) * 4096.0f);
        union { _Float16 hf; unsigned short u; } ch, cl;
        ch.hf = h; cl.hf = lo;
        Th[(size_t)(c0 + ty + i * 8) * R + r0 + tx] = ch.u;
        Tl[(size_t)(c0 + ty + i * 8) * R + r0 + tx] = cl.u;
    }
}

// ---------------- enc1: fp16x2-split MFMA, software-pipelined ---------------
// C_partial[z] = x @ We1 (K-slice z), fp32-accurate via Dekker fp16 split:
//   x = xh + xl/4096, w = wh + wl/4096
//   C = (xh@wh) + 2^-12 * (xh@wl + xl@wh)        (lo*lo ~2^-24, omitted)
template<int BUF>
__device__ __forceinline__ void enc1_step(
    int K0,
    const float* __restrict__ gA,
    const unsigned short* __restrict__ gBh,
    const unsigned short* __restrict__ gBl,
    short (&Ah)[2][2048], short (&Al)[2][2048],
    half8 (&bhC)[4], half8 (&bhN)[4], half8 (&blS)[4],
    f32x4& p0, f32x4& p1,
    f32x4 (&acc1)[4][4], f32x4 (&acc2)[4][4],
    int aoff, int fr0)
{
    constexpr size_t rstep = (size_t)16 * 4096;   // next t-block (16 rows)
    const int kn1 = K0 + 32, kn2 = K0 + 64;
    __syncthreads();   // LDS[BUF] (written last step) visible
#pragma unroll
    for (int j = 0; j < 4; j++)
        blS[j] = *(const half8*)(gBl + (size_t)j * rstep + K0);
    if (kn1 < 2048) {
#pragma unroll
        for (int j = 0; j < 4; j++)
            bhN[j] = *(const half8*)(gBh + (size_t)j * rstep + kn1);
    }
    f32x4 f0, f1;
    if (kn2 < 2048) {
        f0 = __builtin_nontemporal_load((const f32x4*)(gA + kn2));
        f1 = __builtin_nontemporal_load((const f32x4*)(gA + kn2 + 4));
    }
    half8 ah[4];
#pragma unroll
    for (int i = 0; i < 4; i++)
        ah[i] = *(const half8*)&Ah[BUF][(i << 9) + fr0];
#pragma unroll
    for (int i = 0; i < 4; i++)
#pragma unroll
        for (int j = 0; j < 4; j++)
            acc1[i][j] = __builtin_amdgcn_mfma_f32_16x16x32_f16(
                ah[i], bhC[j], acc1[i][j], 0, 0, 0);
#pragma unroll
    for (int i = 0; i < 4; i++)
#pragma unroll
        for (int j = 0; j < 4; j++)
            acc2[i][j] = __builtin_amdgcn_mfma_f32_16x16x32_f16(
                ah[i], blS[j], acc2[i][j], 0, 0, 0);
    half8 al[4];
#pragma unroll
    for (int i = 0; i < 4; i++)
        al[i] = *(const half8*)&Al[BUF][(i << 9) + fr0];
#pragma unroll
    for (int i = 0; i < 4; i++)
#pragma unroll
        for (int j = 0; j < 4; j++)
            acc2[i][j] = __builtin_amdgcn_mfma_f32_16x16x32_f16(
                al[i], bhC[j], acc2[i][j], 0, 0, 0);
    if (kn1 < 2048) {
        float fv[8];
        *(f32x4*)&fv[0] = p0;
        *(f32x4*)&fv[4] = p1;
        union { _Float16 h[8]; short8 s; } uh, ul;
#pragma unroll
        for (int e = 0; e < 8; e++) {
            const float f = fv[e];
            const _Float16 h = (_Float16)f;
            const float fh = (float)h;
            uh.h[e] = h;
            ul.h[e] = (_Float16)((f - fh) * 4096.0f);
        }
        *(short8*)&Ah[BUF ^ 1][aoff] = uh.s;
        *(short8*)&Al[BUF ^ 1][aoff] = ul.s;
    }
    if (kn2 < 2048) { p0 = f0; p1 = f1; }
}

__global__ __launch_bounds__(256, 2) void gemm_f16x2_enc1(
    const float* __restrict__ X,             // 16384 x 4096 f32
    const unsigned short* __restrict__ Bh,   // 256 x 4096 f16 (We1^T hi)
    const unsigned short* __restrict__ Bl,   // 256 x 4096 f16 (We1^T lo*2^12)
    float* __restrict__ part)                // [2][16384][256] f32
{
    __shared__ short Ah[2][2048];    // 4 t-blocks (64 rows) frag-order, 8 KB
    __shared__ short Al[2][2048];
    const int tid = threadIdx.x;
    const int l = tid & 63, w = tid >> 6;     // 4 waves; wave w -> cols w*64
    const int lm = l & 15, lq = l >> 4;
    const int bm = blockIdx.y * 64;
    const int kStart = blockIdx.z * 2048;

    const float* gA = X + (size_t)(bm + w * 16 + lm) * 4096 + kStart + lq * 8;
    const unsigned short* gBh = Bh + (size_t)(w * 64 + lm) * 4096 + kStart + lq * 8;
    const unsigned short* gBl = Bl + (size_t)(w * 64 + lm) * 4096 + kStart + lq * 8;
    constexpr size_t rstep = (size_t)16 * 4096;

    const int aoff = (w << 9) + (l << 3);     // A store slot (shorts)
    const int fr0 = (lq << 7) + (lm << 3);    // frag lane offset

    f32x4 acc1[4][4], acc2[4][4];
#pragma unroll
    for (int i = 0; i < 4; i++)
#pragma unroll
        for (int j = 0; j < 4; j++) {
            acc1[i][j] = (f32x4){0.f, 0.f, 0.f, 0.f};
            acc2[i][j] = (f32x4){0.f, 0.f, 0.f, 0.f};
        }

    half8 bhA[4], bhB[4], blS[4];
    f32x4 p0, p1;

    // prologue: B(0) hi -> bhA; A(0) -> convert -> LDS[0]; A(1) -> p regs
    {
#pragma unroll
        for (int j = 0; j < 4; j++)
            bhA[j] = *(const half8*)(gBh + (size_t)j * rstep);
        f32x4 a0 = __builtin_nontemporal_load((const f32x4*)(gA));
        f32x4 a1 = __builtin_nontemporal_load((const f32x4*)(gA + 4));
        p0 = __builtin_nontemporal_load((const f32x4*)(gA + 32));
        p1 = __builtin_nontemporal_load((const f32x4*)(gA + 36));
        float fv[8];
        *(f32x4*)&fv[0] = a0;
        *(f32x4*)&fv[4] = a1;
        union { _Float16 h[8]; short8 s; } uh, ul;
#pragma unroll
        for (int e = 0; e < 8; e++) {
            const float f = fv[e];
            const _Float16 h = (_Float16)f;
            const float fh = (float)h;
            uh.h[e] = h;
            ul.h[e] = (_Float16)((f - fh) * 4096.0f);
        }
        *(short8*)&Ah[0][aoff] = uh.s;
        *(short8*)&Al[0][aoff] = ul.s;
    }

    for (int k2 = 0; k2 < 2048; k2 += 64) {
        enc1_step<0>(k2,      gA, gBh, gBl, Ah, Al, bhA, bhB, blS,
                     p0, p1, acc1, acc2, aoff, fr0);
        enc1_step<1>(k2 + 32, gA, gBh, gBl, Ah, Al, bhB, bhA, blS,
                     p0, p1, acc1, acc2, aoff, fr0);
    }

    float* P = part + (size_t)blockIdx.z * BB * 256;
    const float inv = 0.000244140625f;   // 2^-12
#pragma unroll
    for (int i = 0; i < 4; i++)
#pragma unroll
        for (int j = 0; j < 4; j++) {
            const int col = w * 64 + j * 16 + lm;
#pragma unroll
            for (int r = 0; r < 4; r++) {
                const int row = bm + i * 16 + lq * 4 + r;
                P[(size_t)row * 256 + col] = acc1[i][j][r] + inv * acc2[i][j][r];
            }
        }
}

// ---------------- mid GEMMs: fp16x2 MFMA, fused bias+leaky ------------------
// C = leaky(A @ W + bias), Dekker fp16x2 (same structure as enc1, no splitK).
// BM=64, 4 waves; wave w owns cols w*(16*NJ)..+16*NJ-1 (NJ frags).
// ACT==0: fp32 out. ACT==1: bf16 out (ushort).
template<int BUF, int NJ, int KLEN>
__device__ __forceinline__ void mid_step(
    int K0,
    const float* __restrict__ gA,
    const unsigned short* __restrict__ gBh,
    const unsigned short* __restrict__ gBl,
    short (&Ah)[2][2048], short (&Al)[2][2048],
    half8 (&bhC)[NJ], half8 (&bhN)[NJ], half8 (&blS)[NJ],
    f32x4& p0, f32x4& p1,
    f32x4 (&acc1)[4][NJ], f32x4 (&acc2)[4][NJ],
    int aoff, int fr0)
{
    constexpr size_t rstep = (size_t)16 * KLEN;
    const int kn1 = K0 + 32, kn2 = K0 + 64;
    __syncthreads();
#pragma unroll
    for (int j = 0; j < NJ; j++)
        blS[j] = *(const half8*)(gBl + (size_t)j * rstep + K0);
    if (kn1 < KLEN) {
#pragma unroll
        for (int j = 0; j < NJ; j++)
            bhN[j] = *(const half8*)(gBh + (size_t)j * rstep + kn1);
    }
    f32x4 f0, f1;
    if (kn2 < KLEN) {
        f0 = *(const f32x4*)(gA + kn2);
        f1 = *(const f32x4*)(gA + kn2 + 4);
    }
    half8 ah[4];
#pragma unroll
    for (int i = 0; i < 4; i++)
        ah[i] = *(const half8*)&Ah[BUF][(i << 9) + fr0];
#pragma unroll
    for (int i = 0; i < 4; i++)
#pragma unroll
        for (int j = 0; j < NJ; j++)
            acc1[i][j] = __builtin_amdgcn_mfma_f32_16x16x32_f16(
                ah[i], bhC[j], acc1[i][j], 0, 0, 0);
#pragma unroll
    for (int i = 0; i < 4; i++)
#pragma unroll
        for (int j = 0; j < NJ; j++)
            acc2[i][j] = __builtin_amdgcn_mfma_f32_16x16x32_f16(
                ah[i], blS[j], acc2[i][j], 0, 0, 0);
    half8 al[4];
#pragma unroll
    for (int i = 0; i < 4; i++)
        al[i] = *(const half8*)&Al[BUF][(i << 9) + fr0];
#pragma unroll
    for (int i = 0; i < 4; i++)
#pragma unroll
        for (int j = 0; j < NJ; j++)
            acc2[i][j] = __builtin_amdgcn_mfma_f32_16x16x32_f16(
                al[i], bhC[j], acc2[i][j], 0, 0, 0);
    if (kn1 < KLEN) {
        float fv[8];
        *(f32x4*)&fv[0] = p0;
        *(f32x4*)&fv[4] = p1;
        union { _Float16 h[8]; short8 s; } uh, ul;
#pragma unroll
        for (int e = 0; e < 8; e++) {
            const float f = fv[e];
            const _Float16 h = (_Float16)f;
            const float fh = (float)h;
            uh.h[e] = h;
            ul.h[e] = (_Float16)((f - fh) * 4096.0f);
        }
        *(short8*)&Ah[BUF ^ 1][aoff] = uh.s;
        *(short8*)&Al[BUF ^ 1][aoff] = ul.s;
    }
    if (kn2 < KLEN) { p0 = f0; p1 = f1; }
}

template<int NJ, int KLEN, int ACT>
__global__ __launch_bounds__(256, 2) void gemm_f16x2_mid(
    const float* __restrict__ A,             // M x KLEN f32 row-major
    const unsigned short* __restrict__ Bh,   // N x KLEN f16 (W^T hi)
    const unsigned short* __restrict__ Bl,   // N x KLEN f16 (W^T lo*2^12)
    const float* __restrict__ bias,
    float* __restrict__ Cf, unsigned short* __restrict__ Cb)
{
    __shared__ short Ah[2][2048];
    __shared__ short Al[2][2048];
    const int tid = threadIdx.x;
    const int l = tid & 63, w = tid >> 6;
    const int lm = l & 15, lq = l >> 4;
    const int bm = blockIdx.y * 64;
    const int bn = blockIdx.x * (64 * NJ);
    const int N = gridDim.x * 64 * NJ;

    const float* gA = A + (size_t)(bm + w * 16 + lm) * KLEN + lq * 8;
    const unsigned short* gBh = Bh + (size_t)(bn + w * (16 * NJ) + lm) * KLEN + lq * 8;
    const unsigned short* gBl = Bl + (size_t)(bn + w * (16 * NJ) + lm) * KLEN + lq * 8;
    constexpr size_t rstep = (size_t)16 * KLEN;

    const int aoff = (w << 9) + (l << 3);
    const int fr0 = (lq << 7) + (lm << 3);

    f32x4 acc1[4][NJ], acc2[4][NJ];
#pragma unroll
    for (int i = 0; i < 4; i++)
#pragma unroll
        for (int j = 0; j < NJ; j++) {
            acc1[i][j] = (f32x4){0.f, 0.f, 0.f, 0.f};
            acc2[i][j] = (f32x4){0.f, 0.f, 0.f, 0.f};
        }

    half8 bhA[NJ], bhB[NJ], blS[NJ];
    f32x4 p0, p1;

    {
#pragma unroll
        for (int j = 0; j < NJ; j++)
            bhA[j] = *(const half8*)(gBh + (size_t)j * rstep);
        f32x4 a0 = *(const f32x4*)(gA);
        f32x4 a1 = *(const f32x4*)(gA + 4);
        p0 = *(const f32x4*)(gA + 32);
        p1 = *(const f32x4*)(gA + 36);
        float fv[8];
        *(f32x4*)&fv[0] = a0;
        *(f32x4*)&fv[4] = a1;
        union { _Float16 h[8]; short8 s; } uh, ul;
#pragma unroll
        for (int e = 0; e < 8; e++) {
            const float f = fv[e];
            const _Float16 h = (_Float16)f;
            const float fh = (float)h;
            uh.h[e] = h;
            ul.h[e] = (_Float16)((f - fh) * 4096.0f);
        }
        *(short8*)&Ah[0][aoff] = uh.s;
        *(short8*)&Al[0][aoff] = ul.s;
    }

    for (int k2 = 0; k2 < KLEN; k2 += 64) {
        mid_step<0, NJ, KLEN>(k2,      gA, gBh, gBl, Ah, Al, bhA, bhB, blS,
                              p0, p1, acc1, acc2, aoff, fr0);
        mid_step<1, NJ, KLEN>(k2 + 32, gA, gBh, gBl, Ah, Al, bhB, bhA, blS,
                              p0, p1, acc1, acc2, aoff, fr0);
    }

    const float inv = 0.000244140625f;   // 2^-12
#pragma unroll
    for (int i = 0; i < 4; i++)
#pragma unroll
        for (int j = 0; j < NJ; j++) {
            const int col = bn + w * (16 * NJ) + j * 16 + lm;
            const float bv = bias[col];
#pragma unroll
            for (int r = 0; r < 4; r++) {
                const int row = bm + i * 16 + lq * 4 + r;
                float v = acc1[i][j][r] + inv * acc2[i][j][r] + bv;
                v = (v > 0.f) ? v : 0.01f * v;
                if (ACT == 0) Cf[(size_t)row * N + col] = v;
                else          Cb[(size_t)row * N + col] = f2bf(v);
            }
        }
}

// ---------------- dec3: bf16 MFMA, X = sigmoid(Ag @ WT^T + bias) ------------
__global__ __launch_bounds__(256) void gemm_bf16_dec3(
    const unsigned short* __restrict__ Ag,   // 16384 x 256 bf16 row-major
    const unsigned short* __restrict__ Bt,   // 4096 x 256 bf16 row-major (Wd3^T)
    const float* __restrict__ bias, float* __restrict__ C)
{
    __shared__ short As[4096];   // 8 KB: 8 t-blocks x 512 shorts
    __shared__ short Bs2[4096];
    const int tid = threadIdx.x;
    const int l = tid & 63, w = tid >> 6;
    const int lm = l & 15, lq = l >> 4;
    const int bm = blockIdx.y * 128, bn = blockIdx.x * 128;
    const int wm = (w >> 1) * 64, wn = (w & 1) * 64;

    const int t0 = w * 2, t1 = w * 2 + 1;
    const unsigned short* ga0 = Ag + (size_t)(bm + t0 * 16 + lm) * 256 + lq * 8;
    const unsigned short* ga1 = Ag + (size_t)(bm + t1 * 16 + lm) * 256 + lq * 8;
    const unsigned short* gb0 = Bt + (size_t)(bn + t0 * 16 + lm) * 256 + lq * 8;
    const unsigned short* gb1 = Bt + (size_t)(bn + t1 * 16 + lm) * 256 + lq * 8;

    f32x4 acc[4][4];
#pragma unroll
    for (int i = 0; i < 4; i++)
#pragma unroll
        for (int j = 0; j < 4; j++) acc[i][j] = (f32x4){0.f, 0.f, 0.f, 0.f};

    for (int k0 = 0; k0 < 256; k0 += 32) {
        __syncthreads();
        GLL16(ga0 + k0, &As[t0 * 512]);
        GLL16(ga1 + k0, &As[t1 * 512]);
        GLL16(gb0 + k0, &Bs2[t0 * 512]);
        GLL16(gb1 + k0, &Bs2[t1 * 512]);
        __syncthreads();
        short8 af[4], bf[4];
#pragma unroll
        for (int i = 0; i < 4; i++)
            af[i] = *(const short8*)&As[((w >> 1) * 4 + i) * 512 + lq * 128 + lm * 8];
#pragma unroll
        for (int j = 0; j < 4; j++)
            bf[j] = *(const short8*)&Bs2[((w & 1) * 4 + j) * 512 + lq * 128 + lm * 8];
#pragma unroll
        for (int i = 0; i < 4; i++)
#pragma unroll
            for (int j = 0; j < 4; j++)
                acc[i][j] = __builtin_amdgcn_mfma_f32_16x16x32_bf16(
                    af[i], bf[j], acc[i][j], 0, 0, 0);
    }

#pragma unroll
    for (int i = 0; i < 4; i++) {
#pragma unroll
        for (int j = 0; j < 4; j++) {
            const int col = bn + wn + j * 16 + lm;
            const float bv = bias[col];
#pragma unroll
            for (int r = 0; r < 4; r++) {
                const int row = bm + wm + i * 16 + lq * 4 + r;
                float v = acc[i][j][r] + bv;
                v = 1.0f / (1.0f + __expf(-v));
                C[(size_t)row * 4096 + col] = v;
            }
        }
    }
}

// ---------------- VQ (unchanged fp32) ---------------------------------------
__global__ __launch_bounds__(512) void vq_argmin(
    const float* __restrict__ ze, const float* __restrict__ cb,
    float* __restrict__ idxf)
{
    __shared__ float cbs[64 * 512];
    __shared__ float As[64][68];
    __shared__ float w2s[512];
    const int tid = threadIdx.x;
    const int p0 = blockIdx.x * 64;

    const float4* cb4 = (const float4*)cb;
    float4* cbs4 = (float4*)cbs;
    for (int i = tid; i < 8192; i += 512) cbs4[i] = cb4[i];

    const float4* ze4 = (const float4*)(ze + (size_t)p0 * 64);
    for (int i = tid; i < 1024; i += 512) {
        float4 v = ze4[i];
        int e = i * 4;
        int bo = e >> 9, r = e & 511;
        int d = r >> 3, m = r & 7;
        *(float4*)&As[d][bo * 8 + m] = v;
    }
    __syncthreads();

    {
        float s = 0.f;
#pragma unroll
        for (int d = 0; d < 64; ++d) { float c = cbs[d * 512 + tid]; s = fmaf(c, c, s); }
        w2s[tid] = s;
    }
    __syncthreads();

    const int tx = tid & 63;
    const int ty = tid >> 6;

    float acc[8][8], x2a[8];
#pragma unroll
    for (int i = 0; i < 8; i++) {
        x2a[i] = 0.f;
#pragma unroll
        for (int j = 0; j < 8; j++) acc[i][j] = 0.f;
    }

#pragma unroll 8
    for (int kk = 0; kk < 64; ++kk) {
        float a[8], b[8];
        *(float4*)&a[0] = *(const float4*)&As[kk][ty * 8];
        *(float4*)&a[4] = *(const float4*)&As[kk][ty * 8 + 4];
        *(float4*)&b[0] = *(const float4*)&cbs[kk * 512 + tx * 8];
        *(float4*)&b[4] = *(const float4*)&cbs[kk * 512 + tx * 8 + 4];
#pragma unroll
        for (int i = 0; i < 8; i++) x2a[i] = fmaf(a[i], a[i], x2a[i]);
#pragma unroll
        for (int i = 0; i < 8; i++)
#pragma unroll
            for (int j = 0; j < 8; j++)
                acc[i][j] = fmaf(a[i], b[j], acc[i][j]);
    }

    float w2v[8];
#pragma unroll
    for (int j = 0; j < 8; j++) w2v[j] = w2s[tx * 8 + j];

#pragma unroll
    for (int i = 0; i < 8; i++) {
        float bd = 3.4e38f; int bk = 1 << 30;
#pragma unroll
        for (int j = 0; j < 8; j++) {
            float dsc = (x2a[i] - 2.0f * acc[i][j]) + w2v[j];
            if (dsc < bd) { bd = dsc; bk = tx * 8 + j; }
        }
        for (int off = 32; off > 0; off >>= 1) {
            float od = __shfl_xor(bd, off);
            int   ok = __shfl_xor(bk, off);
            if (od < bd || (od == bd && ok < bk)) { bd = od; bk = ok; }
        }
        if (tx == i) idxf[p0 + ty * 8 + i] = (float)bk;
    }
}

__global__ __launch_bounds__(256) void vq_gather(
    const float* __restrict__ ze, const float* __restrict__ idxf,
    const float* __restrict__ cb,
    float* __restrict__ zq, float* __restrict__ emb)
{
    const int t = blockIdx.x * 256 + threadIdx.x;
    const int e = t * 4;
    const int b = e >> 9, r = e & 511;
    const int d = r >> 3, m = r & 7;
    const float4 z = *(const float4*)(ze + e);
    float q[4];
#pragma unroll
    for (int c = 0; c < 4; c++) {
        int k = (int)idxf[b * 8 + m + c];
        q[c] = cb[d * 512 + k];
    }
    float4 zq4, em4;
    zq4.x = z.x + (q[0] - z.x); zq4.y = z.y + (q[1] - z.y);
    zq4.z = z.z + (q[2] - z.z); zq4.w = z.w + (q[3] - z.w);
    em4.x = q[0]; em4.y = q[1]; em4.z = q[2]; em4.w = q[3];
    *(float4*)(zq + e) = zq4;
    *(float4*)(emb + e) = em4;
}

extern "C" void kernel_launch(void* const* d_in, const int* in_sizes, int n_in,
                              void* d_out, int out_size, void* d_ws, size_t ws_size,
                              hipStream_t stream)
{
    const float* x   = (const float*)d_in[0];
    const float* We1 = (const float*)d_in[1];
    const float* be1 = (const float*)d_in[2];
    const float* We2 = (const float*)d_in[3];
    const float* be2 = (const float*)d_in[4];
    const float* We3 = (const float*)d_in[5];
    const float* be3 = (const float*)d_in[6];
    const float* Wd1 = (const float*)d_in[7];
    const float* bd1 = (const float*)d_in[8];
    const float* Wd2 = (const float*)d_in[9];
    const float* bd2 = (const float*)d_in[10];
    const float* Wd3 = (const float*)d_in[11];
    const float* bd3 = (const float*)d_in[12];
    const float* cb  = (const float*)d_in[13];

    float* out   = (float*)d_out;
    float* o_idx = out;
    float* o_ze  = o_idx + 131072;
    float* o_zq  = o_ze + 8388608;
    float* o_emb = o_zq + 8388608;
    float* o_X   = o_emb + 8388608;   // 268 MB; doubles as split-K scratch

    float* h1 = (float*)d_ws;                          // B*256 f32
    float* h2 = h1 + (size_t)BB * 256;                 // B*128 f32
    // decoder phase reuse (h1/h2 dead):
    float* g1 = h1;                                    // B*128 f32
    unsigned short* g2b = (unsigned short*)(h1 + (size_t)BB * 128); // B*256 bf16
    unsigned short* WT  = (unsigned short*)h2;         // 4096x256 bf16

    // W^T fp16 hi/lo splits in the high region of o_X (dead until dec3;
    // split-K partials use only the first 8.4M floats of o_X)
    unsigned short* Bth  = (unsigned short*)(o_X + 16777216);  // We1: 2 MB
    unsigned short* Btl  = Bth + 1048576;                      //      2 MB
    unsigned short* W2h  = Btl + 1048576;   // We2^T 128x256
    unsigned short* W2l  = W2h + 32768;
    unsigned short* W3h  = W2l + 32768;     // We3^T 512x128
    unsigned short* W3l  = W3h + 65536;
    unsigned short* Wd1h = W3l + 65536;     // Wd1^T 128x512
    unsigned short* Wd1l = Wd1h + 65536;
    unsigned short* Wd2h = Wd1l + 65536;    // Wd2^T 256x128
    unsigned short* Wd2l = Wd2h + 32768;

    // weight prep (all tiny; WT/h2 prep deferred until h2 is dead)
    transpose_split_f16<<<dim3(8, 128), 256, 0, stream>>>(We1, Bth, Btl, 4096, 256);
    transpose_split_f16<<<dim3(4, 8),   256, 0, stream>>>(We2, W2h, W2l, 256, 128);
    transpose_split_f16<<<dim3(16, 4),  256, 0, stream>>>(We3, W3h, W3l, 128, 512);
    transpose_split_f16<<<dim3(4, 16),  256, 0, stream>>>(Wd1, Wd1h, Wd1l, 512, 128);
    transpose_split_f16<<<dim3(8, 4),   256, 0, stream>>>(Wd2, Wd2h, Wd2l, 128, 256);

    // encoder
    gemm_f16x2_enc1<<<dim3(1, 256, 2), 256, 0, stream>>>(x, Bth, Btl, o_X);
    combine_act<<<4096, 256, 0, stream>>>(o_X, 2, (size_t)BB * 256, be1, 256, h1, nullptr);
    gemm_f16x2_mid<2, 256, 0><<<dim3(1, 256), 256, 0, stream>>>(
        h1, W2h, W2l, be2, h2, nullptr);
    gemm_f16x2_mid<4, 128, 0><<<dim3(2, 256), 256, 0, stream>>>(
        h2, W3h, W3l, be3, o_ze, nullptr);

    // VQ
    vq_argmin<<<dim3(2048), dim3(512), 0, stream>>>(o_ze, cb, o_idx);
    vq_gather<<<dim3(8192), dim3(256), 0, stream>>>(o_ze, o_idx, cb, o_zq, o_emb);

    // Wd3^T cast into h2 (h2 dead after enc3 consumed it)
    transpose_cast<<<dim3(128, 8), 256, 0, stream>>>(Wd3, WT, 256, 4096);

    // decoder
    gemm_f16x2_mid<2, 512, 0><<<dim3(1, 256), 256, 0, stream>>>(
        o_zq, Wd1h, Wd1l, bd1, g1, nullptr);
    gemm_f16x2_mid<4, 128, 1><<<dim3(1, 256), 256, 0, stream>>>(
        g1, Wd2h, Wd2l, bd2, nullptr, g2b);
    gemm_bf16_dec3<<<dim3(32, 128), 256, 0, stream>>>(g2b, WT, bd3, o_X);
}